// Round 4
// baseline (1480.592 us; speedup 1.0000x reference)
//
#include <hip/hip_runtime.h>

#define NLAYER 3
#define NATOM 20000
#define NPROBE 100000
#define NEDGE 400000
#define HD 128
#define NBIN 2048
#define CUTOFFF 4.0f
#define PLANE 16384   // ushorts per bf16 plane (128x128)
#define MT 128        // row tile

typedef unsigned int u32;
typedef unsigned short u16;
typedef __attribute__((ext_vector_type(8))) short bf16x8;
typedef __attribute__((ext_vector_type(4))) float f32x4;

// ---------- math helpers ----------
__device__ __forceinline__ float sspf(float x) {
    return fmaxf(x, 0.f) + __logf(1.f + __expf(-fabsf(x))) - 0.69314718055994530942f;
}
__device__ __forceinline__ float sigf(float x) {
    return 1.f / (1.f + __expf(-x));
}
__device__ __forceinline__ void atomic_add_f(float* p, float v) {
    __hip_atomic_fetch_add(p, v, __ATOMIC_RELAXED, __HIP_MEMORY_SCOPE_AGENT);
}
__device__ __forceinline__ u32 atomic_add_u(u32* p, u32 v) {
    return __hip_atomic_fetch_add(p, v, __ATOMIC_RELAXED, __HIP_MEMORY_SCOPE_AGENT);
}
__device__ __forceinline__ u32 f2u(float f) { union { float f; u32 u; } x; x.f = f; return x.u; }
__device__ __forceinline__ float u2f(u32 u) { union { float f; u32 u; } x; x.u = u; return x.f; }
__device__ __forceinline__ u16 bf16rn(float f) {
    u32 u = f2u(f);
    u32 r = u + 0x7fffu + ((u >> 16) & 1u);
    return (u16)(r >> 16);
}
// pack float -> (hi bf16 rounded | lo bf16 truncated << 16), ~6 VALU
__device__ __forceinline__ u32 packhl(float x) {
    u32 u = f2u(x);
    u32 h = (u + 0x7fffu + ((u >> 16) & 1u)) & 0xffff0000u;
    float lf = x - u2f(h);
    return (h >> 16) | (f2u(lf) & 0xffff0000u);
}
__device__ __forceinline__ u32 lo16pair(u32 a, u32 b) { return (a & 0xffffu) | (b << 16); }
__device__ __forceinline__ u32 hi16pair(u32 a, u32 b) { return (a >> 16) | (b & 0xffff0000u); }
__device__ __forceinline__ bf16x8 mk_bf16x8(u32 a, u32 b, u32 c, u32 d) {
    union { u32 u[4]; bf16x8 v; } x;
    x.u[0] = a; x.u[1] = b; x.u[2] = c; x.u[3] = d;
    return x.v;
}

// ---------- MFMA core: 32 rows/wave (2 sub-tiles), K=128, 3-term split ----------
// LDS: 128 rows x 128 packed u32 (hi|lo bf16), 16B granule g of row r at g^(r&7).
// Wave w rows w*32..w*32+31. acc{0,1}[n][reg]: row = wrow0 + sub*16 + (lane>>4)*4 + reg,
// col = n*16 + (lane&15).
__device__ __forceinline__ void mma2(const u32* __restrict__ lds, int lane, int wrow0,
                                     const u16* __restrict__ Wb,
                                     f32x4 acc0[8], f32x4 acc1[8]) {
    const bf16x8* Bh = (const bf16x8*)Wb;
    const bf16x8* Bl = (const bf16x8*)(Wb + PLANE);
    int r0 = wrow0 + (lane & 15);
    const u32* rp0 = lds + r0 * 128;
    const u32* rp1 = rp0 + 16 * 128;
    int s = r0 & 7;                 // (r0+16)&7 == s
    int kq = (lane >> 4) << 1;
#pragma unroll
    for (int c = 0; c < 4; ++c) {
        int g0 = c * 8 + kq;
        int o0 = (g0 ^ s) << 2, o1 = ((g0 + 1) ^ s) << 2;
        u32 a0 = rp0[o0 + 0], a1v = rp0[o0 + 1], a2 = rp0[o0 + 2], a3 = rp0[o0 + 3];
        u32 b0 = rp0[o1 + 0], b1v = rp0[o1 + 1], b2 = rp0[o1 + 2], b3 = rp0[o1 + 3];
        bf16x8 Ah0 = mk_bf16x8(lo16pair(a0, a1v), lo16pair(a2, a3), lo16pair(b0, b1v), lo16pair(b2, b3));
        bf16x8 Al0 = mk_bf16x8(hi16pair(a0, a1v), hi16pair(a2, a3), hi16pair(b0, b1v), hi16pair(b2, b3));
        u32 c0 = rp1[o0 + 0], c1 = rp1[o0 + 1], c2 = rp1[o0 + 2], c3 = rp1[o0 + 3];
        u32 d0 = rp1[o1 + 0], d1 = rp1[o1 + 1], d2 = rp1[o1 + 2], d3 = rp1[o1 + 3];
        bf16x8 Ah1 = mk_bf16x8(lo16pair(c0, c1), lo16pair(c2, c3), lo16pair(d0, d1), lo16pair(d2, d3));
        bf16x8 Al1 = mk_bf16x8(hi16pair(c0, c1), hi16pair(c2, c3), hi16pair(d0, d1), hi16pair(d2, d3));
        const bf16x8* bh = Bh + (size_t)(c * 8) * 64 + lane;
        const bf16x8* bl = Bl + (size_t)(c * 8) * 64 + lane;
#pragma unroll
        for (int n = 0; n < 8; ++n) {
            bf16x8 vh = bh[n * 64];
            bf16x8 vl = bl[n * 64];
            acc0[n] = __builtin_amdgcn_mfma_f32_16x16x32_bf16(Ah0, vh, acc0[n], 0, 0, 0);
            acc0[n] = __builtin_amdgcn_mfma_f32_16x16x32_bf16(Al0, vh, acc0[n], 0, 0, 0);
            acc0[n] = __builtin_amdgcn_mfma_f32_16x16x32_bf16(Ah0, vl, acc0[n], 0, 0, 0);
            acc1[n] = __builtin_amdgcn_mfma_f32_16x16x32_bf16(Ah1, vh, acc1[n], 0, 0, 0);
            acc1[n] = __builtin_amdgcn_mfma_f32_16x16x32_bf16(Al1, vh, acc1[n], 0, 0, 0);
            acc1[n] = __builtin_amdgcn_mfma_f32_16x16x32_bf16(Ah1, vl, acc1[n], 0, 0, 0);
        }
    }
}

// stage 128 fp32 rows -> packed LDS. thread t: rows (t>>2) and 64+(t>>2), quarter t&3.
__device__ __forceinline__ void stage_pack2(const float* __restrict__ A, int M,
                                            int m0, int t, u32* lds) {
#pragma unroll
    for (int b = 0; b < 2; ++b) {
        int r = b * 64 + (t >> 2), q = t & 3;
        int row = m0 + r;
        bool ok = row < M;
        const float4* src = (const float4*)(A + (size_t)row * HD + q * 32);
        int s = r & 7;
#pragma unroll
        for (int i4 = 0; i4 < 8; ++i4) {
            float4 v = ok ? src[i4] : make_float4(0.f, 0.f, 0.f, 0.f);
            u32 p0 = packhl(v.x), p1 = packhl(v.y), p2 = packhl(v.z), p3 = packhl(v.w);
            *(uint4*)(lds + r * 128 + (((q * 8 + i4) ^ s) << 2)) = make_uint4(p0, p1, p2, p3);
        }
    }
}

// write ssp(acc+bias) for both subs back to LDS (packed, swizzled)
__device__ __forceinline__ void h_to_lds2(u32* lds, int wrow0, int lq, int l15,
                                          const f32x4 a0[8], const f32x4 a1[8],
                                          const float* __restrict__ bias) {
#pragma unroll
    for (int n = 0; n < 8; ++n) {
        int col = n * 16 + l15;
        float bb = bias[col];
#pragma unroll
        for (int r = 0; r < 4; ++r) {
            int r0 = wrow0 + lq * 4 + r;
            lds[r0 * 128 + (((col >> 2) ^ (r0 & 7)) << 2) + (col & 3)] = packhl(sspf(a0[n][r] + bb));
            int r1 = r0 + 16;
            lds[r1 * 128 + (((col >> 2) ^ (r1 & 7)) << 2) + (col & 3)] = packhl(sspf(a1[n][r] + bb));
        }
    }
}

// ---------- weight conversion ----------
__global__ void convert_w_k(const float* __restrict__ Wn1, const float* __restrict__ Wn2,
                            const float* __restrict__ gW1, const float* __restrict__ gW2,
                            const float* __restrict__ tW1, const float* __restrict__ tW2,
                            const float* __restrict__ rW1, u16* __restrict__ Wb) {
    int m = blockIdx.x;
    const float* src;
    if (m < 6)       src = Wn1 + (size_t)(m >> 1) * (2 * HD * HD) + (size_t)(m & 1) * (HD * HD);
    else if (m < 9)  src = Wn2 + (size_t)(m - 6) * HD * HD;
    else if (m < 12) src = gW1 + (size_t)(m - 9) * HD * HD;
    else if (m < 15) src = gW2 + (size_t)(m - 12) * HD * HD;
    else if (m < 18) src = tW1 + (size_t)(m - 15) * HD * HD;
    else if (m < 21) src = tW2 + (size_t)(m - 18) * HD * HD;
    else             src = rW1;
    int t = threadIdx.x;
    int lane = t & 63, nn = t >> 6;
    u16* dh = Wb + (size_t)m * (2 * PLANE);
    u16* dl = dh + PLANE;
    for (int c = 0; c < 4; ++c) {
        for (int hh = 0; hh < 2; ++hh) {
            int n = nn + hh * 4;
            int col = n * 16 + (lane & 15);
            int k0 = c * 32 + (lane >> 4) * 8;
            u32 hv[4], lv[4];
#pragma unroll
            for (int jj = 0; jj < 4; ++jj) {
                float wA = src[(size_t)(k0 + 2 * jj) * HD + col];
                float wB = src[(size_t)(k0 + 2 * jj + 1) * HD + col];
                u16 ha = bf16rn(wA), hb = bf16rn(wB);
                u16 la = bf16rn(wA - u2f((u32)ha << 16));
                u16 lb = bf16rn(wB - u2f((u32)hb << 16));
                hv[jj] = (u32)ha | ((u32)hb << 16);
                lv[jj] = (u32)la | ((u32)lb << 16);
            }
            size_t off = ((size_t)(c * 8 + n) * 64 + lane) * 8;
            *(uint4*)(dh + off) = make_uint4(hv[0], hv[1], hv[2], hv[3]);
            *(uint4*)(dl + off) = make_uint4(lv[0], lv[1], lv[2], lv[3]);
        }
    }
}

// ---------- gates lookup table ----------
__global__ void gate_table_k(const float* __restrict__ We1, const float* __restrict__ be1,
                             const float* __restrict__ We2, const float* __restrict__ be2,
                             float* __restrict__ gtab) {
    int row = blockIdx.x;
    int l = row / (NBIN + 1);
    int i = row % (NBIN + 1);
    int j = threadIdx.x;
    float d = (CUTOFFF / NBIN) * (float)i;
    __shared__ float h1[HD];
    const float* w1 = We1 + (size_t)l * 16 * HD;
    float acc = be1[l * HD + j];
#pragma unroll
    for (int k = 0; k < 16; ++k) {
        float dd = d - 0.25f * (float)k;
        float es = __expf(-dd * dd * 8.0f);
        acc = fmaf(es, w1[k * HD + j], acc);
    }
    h1[j] = sspf(acc);
    __syncthreads();
    const float* w2 = We2 + (size_t)l * HD * HD;
    float acc2 = be2[l * HD + j];
    for (int k = 0; k < HD; ++k) acc2 = fmaf(h1[k], w2[k * HD + j], acc2);
    float sc = 1.f - sigf(5.f * (d - (CUTOFFF - 1.5f)));
    gtab[(size_t)row * HD + j] = acc2 * sc;
}

// ---------- CSR sort kernels ----------
__global__ __launch_bounds__(256) void hist_k(const int* __restrict__ pe, u32* __restrict__ cnt) {
    int e = blockIdx.x * 256 + threadIdx.x;
    if (e < NEDGE) atomic_add_u(&cnt[pe[2 * e + 1]], 1u);
}

__global__ __launch_bounds__(1024) void scan_k(const u32* __restrict__ cnt, u32* __restrict__ cur) {
    __shared__ u32 sums[1024];
    int t = threadIdx.x;
    const int CH = (NPROBE + 1023) / 1024;
    int lo = t * CH, hi = lo + CH;
    if (hi > NPROBE) hi = NPROBE;
    u32 s = 0;
    for (int i = lo; i < hi; ++i) s += cnt[i];
    sums[t] = s;
    __syncthreads();
    for (int d = 1; d < 1024; d <<= 1) {
        u32 v = (t >= d) ? sums[t - d] : 0u;
        __syncthreads();
        sums[t] += v;
        __syncthreads();
    }
    u32 base = (t == 0) ? 0u : sums[t - 1];
    for (int i = lo; i < hi; ++i) {
        cur[i] = base;
        base += cnt[i];
    }
}

__global__ __launch_bounds__(256) void scatter_k(const int* __restrict__ pe,
                                                 u32* __restrict__ cur, u32* __restrict__ eord) {
    int e = blockIdx.x * 256 + threadIdx.x;
    if (e < NEDGE) {
        u32 pos = atomic_add_u(&cur[pe[2 * e + 1]], 1u);
        eord[pos] = (u32)e;
    }
}

// ---------- batched atom projection: Xa3[l] = atom_rep[l] @ Wn1_atom[l] ----------
#define ABLK 157
__global__ __launch_bounds__(256, 2) void gemm_atoms_k(const float* __restrict__ atom_rep,
                                                       const u16* __restrict__ Wb,
                                                       float* __restrict__ Xa3) {
    __shared__ u32 lds[MT * 128];
    int l = blockIdx.x / ABLK;
    int mb = blockIdx.x % ABLK;
    const float* A = atom_rep + (size_t)l * NATOM * HD;
    const u16* W = Wb + (size_t)(2 * l) * 2 * PLANE;
    float* outp = Xa3 + (size_t)l * NATOM * HD;
    int m0 = mb * MT, t = threadIdx.x;
    stage_pack2(A, NATOM, m0, t, lds);
    __syncthreads();
    int lane = t & 63, wrow0 = (t >> 6) * 32;
    int l15 = lane & 15, lq = lane >> 4;
    f32x4 a0[8] = {}, a1[8] = {};
    mma2(lds, lane, wrow0, W, a0, a1);
#pragma unroll
    for (int r = 0; r < 4; ++r) {
        int row0 = m0 + wrow0 + lq * 4 + r;
        if (row0 < NATOM) {
            float* op = outp + (size_t)row0 * HD + l15;
#pragma unroll
            for (int n = 0; n < 8; ++n) op[n * 16] = a0[n][r];
        }
        int row1 = row0 + 16;
        if (row1 < NATOM) {
            float* op = outp + (size_t)row1 * HD + l15;
#pragma unroll
            for (int n = 0; n < 8; ++n) op[n * 16] = a1[n][r];
        }
    }
}

// ---------- edge scatter helper: gate + run-merge + atomics for one 4-row group ----------
__device__ __forceinline__ void edge_scatter(f32x4 acc[8], int erbase, int e0,
        const int* __restrict__ pe, const u32* __restrict__ eord,
        const float* __restrict__ dist, const float* __restrict__ gtab,
        const float* b2v, int l15, float* __restrict__ msgsum) {
    int rcvr[4];
    float fr[4];
    const float* gp[4];
#pragma unroll
    for (int r = 0; r < 4; ++r) {
        int e = (int)eord[e0 + erbase + r];
        rcvr[r] = pe[2 * e + 1];
        float x = dist[e] * ((float)NBIN / CUTOFFF);
        int i = (int)x;
        i = i < (NBIN - 1) ? i : (NBIN - 1);
        fr[r] = x - (float)i;
        gp[r] = gtab + (size_t)i * HD;
    }
#pragma unroll
    for (int n = 0; n < 8; ++n) {
        int col = n * 16 + l15;
#pragma unroll
        for (int r = 0; r < 4; ++r) {
            float ga = gp[r][col], gb = gp[r][HD + col];
            acc[n][r] = (acc[n][r] + b2v[n]) * fmaf(gb - ga, fr[r], ga);
        }
    }
#pragma unroll
    for (int r = 3; r >= 1; --r) {
        if (rcvr[r] == rcvr[r - 1]) {
#pragma unroll
            for (int n = 0; n < 8; ++n) acc[n][r - 1] += acc[n][r];
        } else {
            float* dst = msgsum + (size_t)rcvr[r] * HD + l15;
#pragma unroll
            for (int n = 0; n < 8; ++n) atomic_add_f(dst + n * 16, acc[n][r]);
        }
    }
    float* dst = msgsum + (size_t)rcvr[0] * HD + l15;
#pragma unroll
    for (int n = 0; n < 8; ++n) atomic_add_f(dst + n * 16, acc[n][0]);
}

// ---------- edge kernel (receiver-sorted, M=128) ----------
__global__ __launch_bounds__(256, 2) void edge_msg_mfma_k(
        const float* __restrict__ Xa, const float* __restrict__ Xp,
        const float* __restrict__ bn1, const u16* __restrict__ W2b,
        const float* __restrict__ bn2, const float* __restrict__ gtab,
        const float* __restrict__ dist, const int* __restrict__ pe,
        const u32* __restrict__ eord, float* __restrict__ msgsum) {
    __shared__ u32 lds[MT * 128];
    int e0 = blockIdx.x * MT;
    int t = threadIdx.x;
#pragma unroll
    for (int b = 0; b < 2; ++b) {
        int r = b * 64 + (t >> 2), q = t & 3;
        int e = (int)eord[e0 + r];
        int snd = pe[2 * e], rcv = pe[2 * e + 1];
        const float4* xa = (const float4*)(Xa + (size_t)snd * HD + q * 32);
        const float4* xp = (const float4*)(Xp + (size_t)rcv * HD + q * 32);
        const float4* bb = (const float4*)(bn1 + q * 32);
        int s = r & 7;
#pragma unroll
        for (int i4 = 0; i4 < 8; ++i4) {
            float4 va = xa[i4], vp = xp[i4], vb = bb[i4];
            u32 p0 = packhl(sspf(va.x + vp.x + vb.x));
            u32 p1 = packhl(sspf(va.y + vp.y + vb.y));
            u32 p2 = packhl(sspf(va.z + vp.z + vb.z));
            u32 p3 = packhl(sspf(va.w + vp.w + vb.w));
            *(uint4*)(lds + r * 128 + (((q * 8 + i4) ^ s) << 2)) = make_uint4(p0, p1, p2, p3);
        }
    }
    __syncthreads();
    int lane = t & 63, wrow0 = (t >> 6) * 32;
    int l15 = lane & 15, lq = lane >> 4;
    f32x4 acc0[8] = {}, acc1[8] = {};
    mma2(lds, lane, wrow0, W2b, acc0, acc1);
    float b2v[8];
#pragma unroll
    for (int n = 0; n < 8; ++n) b2v[n] = bn2[n * 16 + l15];
    edge_scatter(acc0, wrow0 + lq * 4, e0, pe, eord, dist, gtab, b2v, l15, msgsum);
    edge_scatter(acc1, wrow0 + 16 + lq * 4, e0, pe, eord, dist, gtab, b2v, l15, msgsum);
}

// ---------- fused probe update (+Xp projection or readout) ----------
__global__ __launch_bounds__(256, 2) void probe_update_k(
        const float* __restrict__ ps, const float* __restrict__ msgsum,
        const u16* __restrict__ gW1b, const float* __restrict__ gb1,
        const u16* __restrict__ gW2b, const float* __restrict__ gb2,
        const u16* __restrict__ tW1b, const float* __restrict__ tb1,
        const u16* __restrict__ tW2b, const float* __restrict__ tb2,
        const u16* __restrict__ W3b,
        const u16* __restrict__ rW1b, const float* __restrict__ rb1,
        const float* __restrict__ rW2, const float* __restrict__ rb2,
        float* __restrict__ psout, float* __restrict__ xpout,
        float* __restrict__ outp) {
    __shared__ u32 lds[MT * 128];
    int m0 = blockIdx.x * MT, t = threadIdx.x;
    int lane = t & 63, wrow0 = (t >> 6) * 32;
    int l15 = lane & 15, lq = lane >> 4;

    // ---- gate path: g = sigmoid(MLP_g(ps)) ----
    stage_pack2(ps, NPROBE, m0, t, lds);
    __syncthreads();
    f32x4 g0[8] = {}, g1[8] = {};
    mma2(lds, lane, wrow0, gW1b, g0, g1);
    __syncthreads();
    h_to_lds2(lds, wrow0, lq, l15, g0, g1, gb1);
    __syncthreads();
#pragma unroll
    for (int n = 0; n < 8; ++n) { g0[n] = (f32x4){0.f,0.f,0.f,0.f}; g1[n] = (f32x4){0.f,0.f,0.f,0.f}; }
    mma2(lds, lane, wrow0, gW2b, g0, g1);
#pragma unroll
    for (int n = 0; n < 8; ++n) {
        float bb = gb2[n * 16 + l15];
#pragma unroll
        for (int r = 0; r < 4; ++r) {
            g0[n][r] = sigf(g0[n][r] + bb);
            g1[n][r] = sigf(g1[n][r] + bb);
        }
    }
    // ---- trans path: t = MLP_t(msgsum) ----
    __syncthreads();
    stage_pack2(msgsum, NPROBE, m0, t, lds);
    __syncthreads();
    f32x4 tv0[8] = {}, tv1[8] = {};
    mma2(lds, lane, wrow0, tW1b, tv0, tv1);
    __syncthreads();
    h_to_lds2(lds, wrow0, lq, l15, tv0, tv1, tb1);
    __syncthreads();
#pragma unroll
    for (int n = 0; n < 8; ++n) { tv0[n] = (f32x4){0.f,0.f,0.f,0.f}; tv1[n] = (f32x4){0.f,0.f,0.f,0.f}; }
    mma2(lds, lane, wrow0, tW2b, tv0, tv1);

    // ---- combine: ps_new = ps*g + (1-g)*t ----
    bool proj = (W3b != nullptr) || (rW1b != nullptr);
    if (proj) __syncthreads();
#pragma unroll
    for (int n = 0; n < 8; ++n) {
        int col = n * 16 + l15;
        float bb = tb2[col];
#pragma unroll
        for (int r = 0; r < 4; ++r) {
            int lr0 = wrow0 + lq * 4 + r;
            int row0 = m0 + lr0;
            float val0 = 0.f;
            if (row0 < NPROBE) {
                size_t idx = (size_t)row0 * HD + col;
                float tval = tv0[n][r] + bb;
                val0 = fmaf(ps[idx] - tval, g0[n][r], tval);
                psout[idx] = val0;
            }
            if (proj) lds[lr0 * 128 + (((col >> 2) ^ (lr0 & 7)) << 2) + (col & 3)] = packhl(val0);
            int lr1 = lr0 + 16;
            int row1 = row0 + 16;
            float val1 = 0.f;
            if (row1 < NPROBE) {
                size_t idx = (size_t)row1 * HD + col;
                float tval = tv1[n][r] + bb;
                val1 = fmaf(ps[idx] - tval, g1[n][r], tval);
                psout[idx] = val1;
            }
            if (proj) lds[lr1 * 128 + (((col >> 2) ^ (lr1 & 7)) << 2) + (col & 3)] = packhl(val1);
        }
    }
    if (W3b) {
        // Xp = ps_new @ Wn1_probe(next layer)
        __syncthreads();
        f32x4 a0[8] = {}, a1[8] = {};
        mma2(lds, lane, wrow0, W3b, a0, a1);
#pragma unroll
        for (int r = 0; r < 4; ++r) {
            int row0 = m0 + wrow0 + lq * 4 + r;
            if (row0 < NPROBE) {
                float* op = xpout + (size_t)row0 * HD + l15;
#pragma unroll
                for (int n = 0; n < 8; ++n) op[n * 16] = a0[n][r];
            }
            int row1 = row0 + 16;
            if (row1 < NPROBE) {
                float* op = xpout + (size_t)row1 * HD + l15;
#pragma unroll
                for (int n = 0; n < 8; ++n) op[n * 16] = a1[n][r];
            }
        }
    } else if (rW1b) {
        // readout: out = ssp(ps_new @ rW1 + rb1) @ rW2 + rb2
        __syncthreads();
        f32x4 a0[8] = {}, a1[8] = {};
        mma2(lds, lane, wrow0, rW1b, a0, a1);
        float w2v[8], b1v[8];
#pragma unroll
        for (int n = 0; n < 8; ++n) {
            w2v[n] = rW2[n * 16 + l15];
            b1v[n] = rb1[n * 16 + l15];
        }
        float rb2v = rb2[0];
#pragma unroll
        for (int r = 0; r < 4; ++r) {
            float p0 = 0.f, p1 = 0.f;
#pragma unroll
            for (int n = 0; n < 8; ++n) {
                p0 += sspf(a0[n][r] + b1v[n]) * w2v[n];
                p1 += sspf(a1[n][r] + b1v[n]) * w2v[n];
            }
            p0 += __shfl_xor(p0, 1, 16); p0 += __shfl_xor(p0, 2, 16);
            p0 += __shfl_xor(p0, 4, 16); p0 += __shfl_xor(p0, 8, 16);
            p1 += __shfl_xor(p1, 1, 16); p1 += __shfl_xor(p1, 2, 16);
            p1 += __shfl_xor(p1, 4, 16); p1 += __shfl_xor(p1, 8, 16);
            if (l15 == 0) {
                int row0 = m0 + wrow0 + lq * 4 + r;
                if (row0 < NPROBE) outp[row0] = p0 + rb2v;
                if (row0 + 16 < NPROBE) outp[row0 + 16] = p1 + rb2v;
            }
        }
    }
}

// ---------- launcher ----------
extern "C" void kernel_launch(void* const* d_in, const int* in_sizes, int n_in,
                              void* d_out, int out_size, void* d_ws, size_t ws_size,
                              hipStream_t stream) {
    const float* atom_rep = (const float*)d_in[0];
    const float* dist     = (const float*)d_in[1];
    const float* We1 = (const float*)d_in[2];
    const float* be1 = (const float*)d_in[3];
    const float* We2 = (const float*)d_in[4];
    const float* be2 = (const float*)d_in[5];
    const float* Wn1 = (const float*)d_in[6];
    const float* bn1 = (const float*)d_in[7];
    const float* Wn2 = (const float*)d_in[8];
    const float* bn2 = (const float*)d_in[9];
    const float* gW1 = (const float*)d_in[10];
    const float* gb1 = (const float*)d_in[11];
    const float* gW2 = (const float*)d_in[12];
    const float* gb2 = (const float*)d_in[13];
    const float* tW1 = (const float*)d_in[14];
    const float* tb1 = (const float*)d_in[15];
    const float* tW2 = (const float*)d_in[16];
    const float* tb2 = (const float*)d_in[17];
    const float* rW1 = (const float*)d_in[18];
    const float* rb1 = (const float*)d_in[19];
    const float* rW2 = (const float*)d_in[20];
    const float* rb2 = (const float*)d_in[21];
    const int*   pe  = (const int*)d_in[22];
    float* out = (float*)d_out;

    float* ws = (float*)d_ws;
    float* ps     = ws;                         // 12,800,000 f
    float* msgsum = ps + 12800000u;             // 12,800,000 f
    float* Xp     = msgsum + 12800000u;         // 12,800,000 f
    float* Xa3    = Xp + 12800000u;             // 3 * 2,560,000 f
    float* gtab   = Xa3 + 7680000u;             // 786,816 f
    u16*   Wb     = (u16*)(gtab + 786816u);     // 22*2*PLANE u16
    u32*   cnt    = (u32*)(Wb + 22 * 2 * PLANE);
    u32*   cur    = cnt + NPROBE;
    u32*   eord   = cur + NPROBE;

    const int PBLK = (NPROBE + MT - 1) / MT;   // 782
    const int EBLK = NEDGE / MT;               // 3125
    const int TBLK = (NEDGE + 255) / 256;      // 1563

    hipMemsetAsync(ps, 0, 12800000ull * 4, stream);
    hipMemsetAsync(Xp, 0, 12800000ull * 4, stream);
    hipMemsetAsync(cnt, 0, (size_t)NPROBE * 4, stream);
    convert_w_k<<<22, 256, 0, stream>>>(Wn1, Wn2, gW1, gW2, tW1, tW2, rW1, Wb);
    gate_table_k<<<NLAYER * (NBIN + 1), HD, 0, stream>>>(We1, be1, We2, be2, gtab);
    hist_k<<<TBLK, 256, 0, stream>>>(pe, cnt);
    scan_k<<<1, 1024, 0, stream>>>(cnt, cur);
    scatter_k<<<TBLK, 256, 0, stream>>>(pe, cur, eord);
    gemm_atoms_k<<<NLAYER * ABLK, 256, 0, stream>>>(atom_rep, Wb, Xa3);

    for (int l = 0; l < NLAYER; ++l) {
        hipMemsetAsync(msgsum, 0, 12800000ull * 4, stream);
        edge_msg_mfma_k<<<EBLK, 256, 0, stream>>>(Xa3 + (size_t)l * NATOM * HD, Xp,
                                                  bn1 + l * HD,
                                                  Wb + (size_t)(6 + l) * 2 * PLANE,
                                                  bn2 + l * HD,
                                                  gtab + (size_t)l * (NBIN + 1) * HD,
                                                  dist, pe, eord, msgsum);
        const u16* W3  = (l < NLAYER - 1) ? Wb + (size_t)(2 * (l + 1) + 1) * 2 * PLANE : nullptr;
        const u16* RW1 = (l == NLAYER - 1) ? Wb + (size_t)21 * 2 * PLANE : nullptr;
        probe_update_k<<<PBLK, 256, 0, stream>>>(ps, msgsum,
                                                 Wb + (size_t)(9 + l) * 2 * PLANE, gb1 + l * HD,
                                                 Wb + (size_t)(12 + l) * 2 * PLANE, gb2 + l * HD,
                                                 Wb + (size_t)(15 + l) * 2 * PLANE, tb1 + l * HD,
                                                 Wb + (size_t)(18 + l) * 2 * PLANE, tb2 + l * HD,
                                                 W3, RW1, rb1, rW2, rb2,
                                                 ps, Xp, out);
    }
}

// Round 5
// 987.948 us; speedup vs baseline: 1.4987x; 1.4987x over previous
//
#include <hip/hip_runtime.h>

#define NLAYER 3
#define NATOM 20000
#define NPROBE 100000
#define NEDGE 400000
#define HD 128
#define NBIN 2048
#define CUTOFFF 4.0f
#define PLANE 16384   // ushorts per bf16 plane (128x128)
#define MT 64         // row tile
#define NT 512        // threads per block (8 waves)

typedef unsigned int u32;
typedef unsigned short u16;
typedef __attribute__((ext_vector_type(8))) short bf16x8;
typedef __attribute__((ext_vector_type(4))) float f32x4;

// ---------- math helpers ----------
__device__ __forceinline__ float sspf(float x) {
    // ln(1+e^x) - ln2 = ln2*(log2(1+2^(x*log2e)) - 1); 2 trans ops
    float e = __builtin_amdgcn_exp2f(fminf(x, 80.f) * 1.44269504088896341f);
    return 0.69314718055994531f * (__builtin_amdgcn_logf(1.f + e) - 1.f);
}
__device__ __forceinline__ float sigf(float x) {
    return 1.f / (1.f + __builtin_amdgcn_exp2f(-x * 1.44269504088896341f));
}
__device__ __forceinline__ void atomic_add_f(float* p, float v) {
    __hip_atomic_fetch_add(p, v, __ATOMIC_RELAXED, __HIP_MEMORY_SCOPE_AGENT);
}
__device__ __forceinline__ u32 atomic_add_u(u32* p, u32 v) {
    return __hip_atomic_fetch_add(p, v, __ATOMIC_RELAXED, __HIP_MEMORY_SCOPE_AGENT);
}
__device__ __forceinline__ u32 f2u(float f) { union { float f; u32 u; } x; x.f = f; return x.u; }
__device__ __forceinline__ float u2f(u32 u) { union { float f; u32 u; } x; x.u = u; return x.f; }
__device__ __forceinline__ u16 bf16rn(float f) {
    u32 u = f2u(f);
    u32 r = u + 0x7fffu + ((u >> 16) & 1u);
    return (u16)(r >> 16);
}
// split x,y -> hi-pair (rounded) and lo-pair (truncated residual)
__device__ __forceinline__ void split_pair(float x, float y, u32& hi, u32& lo) {
    u32 ux = f2u(x);
    u32 hx = (ux + 0x7fffu + ((ux >> 16) & 1u)) & 0xffff0000u;
    float lxf = x - u2f(hx);
    u32 uy = f2u(y);
    u32 hy = (uy + 0x7fffu + ((uy >> 16) & 1u)) & 0xffff0000u;
    float lyf = y - u2f(hy);
    hi = (hx >> 16) | hy;
    lo = (f2u(lxf) >> 16) | (f2u(lyf) & 0xffff0000u);
}

// ---------- MFMA core: weight-stationary column slice ----------
// LDS: split planes ldsH/ldsL, u16[64][128]; 16B granule gc (8 bf16) of row r
// stored at slot gc ^ (r&7).
// Wave `wid` owns cols wid*16..+15; holds B frags in regs; sweeps 64 rows.
// acc[m][reg]: row = m*16 + (lane>>4)*4 + reg, col = wid*16 + (lane&15).
__device__ __forceinline__ void mma_slice(const u16* __restrict__ ldsH,
                                          const u16* __restrict__ ldsL,
                                          int lane, int wid,
                                          const u16* __restrict__ Wb,
                                          f32x4 acc[4]) {
    const bf16x8* Bhp = (const bf16x8*)Wb;
    const bf16x8* Blp = (const bf16x8*)(Wb + PLANE);
    bf16x8 Bh[4], Bl[4];
#pragma unroll
    for (int c = 0; c < 4; ++c) {
        Bh[c] = Bhp[(size_t)(c * 8 + wid) * 64 + lane];
        Bl[c] = Blp[(size_t)(c * 8 + wid) * 64 + lane];
    }
    int l15 = lane & 15, kq = lane >> 4;
#pragma unroll
    for (int m = 0; m < 4; ++m) {
        int row = m * 16 + l15;
        int s = row & 7;
        const u16* hp = ldsH + row * 128;
        const u16* lp = ldsL + row * 128;
#pragma unroll
        for (int c = 0; c < 4; ++c) {
            int off = ((c * 4 + kq) ^ s) << 3;
            bf16x8 Ah = *(const bf16x8*)(hp + off);
            bf16x8 Al = *(const bf16x8*)(lp + off);
            acc[m] = __builtin_amdgcn_mfma_f32_16x16x32_bf16(Ah, Bh[c], acc[m], 0, 0, 0);
            acc[m] = __builtin_amdgcn_mfma_f32_16x16x32_bf16(Al, Bh[c], acc[m], 0, 0, 0);
            acc[m] = __builtin_amdgcn_mfma_f32_16x16x32_bf16(Ah, Bl[c], acc[m], 0, 0, 0);
        }
    }
}

// stage 64 fp32 rows -> split planes. thread t: row t>>3, 16-col chunk (t&7)*16.
__device__ __forceinline__ void stage_split(const float* __restrict__ A, int M,
                                            int m0, int t, u16* ldsH, u16* ldsL) {
    int r = t >> 3, q = t & 7;
    int row = m0 + r;
    bool ok = row < M;
    const float4* src = (const float4*)(A + (size_t)row * HD + q * 16);
    int s = r & 7;
#pragma unroll
    for (int j = 0; j < 4; ++j) {
        float4 v = ok ? src[j] : make_float4(0.f, 0.f, 0.f, 0.f);
        u32 h0, l0, h1, l1;
        split_pair(v.x, v.y, h0, l0);
        split_pair(v.z, v.w, h1, l1);
        int gc = q * 2 + (j >> 1);
        int off = r * 128 + ((gc ^ s) << 3) + (j & 1) * 4;
        *(uint2*)(ldsH + off) = make_uint2(h0, h1);
        *(uint2*)(ldsL + off) = make_uint2(l0, l1);
    }
}

// producer writes ssp(acc+bias) back to split planes (own col-slice, all rows)
__device__ __forceinline__ void h_store(u16* ldsH, u16* ldsL, int wid, int lane,
                                        const f32x4 acc[4], const float* __restrict__ bias) {
    int l15 = lane & 15, lq = lane >> 4;
    int col = wid * 16 + l15;
    float bb = bias[col];
    int gc = col >> 3, wg = col & 7;
#pragma unroll
    for (int m = 0; m < 4; ++m) {
#pragma unroll
        for (int r = 0; r < 4; ++r) {
            int row = m * 16 + lq * 4 + r;
            float h = sspf(acc[m][r] + bb);
            u32 u = f2u(h);
            u32 hh = (u + 0x7fffu + ((u >> 16) & 1u)) & 0xffff0000u;
            float lf = h - u2f(hh);
            int off = row * 128 + ((gc ^ (row & 7)) << 3) + wg;
            ldsH[off] = (u16)(hh >> 16);
            ldsL[off] = (u16)(f2u(lf) >> 16);
        }
    }
}

// store raw value (no activation) to planes
__device__ __forceinline__ void v_store(u16* ldsH, u16* ldsL, int wid, int lane,
                                        int m, int r, float val) {
    int l15 = lane & 15, lq = lane >> 4;
    int col = wid * 16 + l15;
    int gc = col >> 3, wg = col & 7;
    int row = m * 16 + lq * 4 + r;
    u32 u = f2u(val);
    u32 hh = (u + 0x7fffu + ((u >> 16) & 1u)) & 0xffff0000u;
    float lf = val - u2f(hh);
    int off = row * 128 + ((gc ^ (row & 7)) << 3) + wg;
    ldsH[off] = (u16)(hh >> 16);
    ldsL[off] = (u16)(f2u(lf) >> 16);
}

// ---------- weight conversion (frag-swizzled hi/lo planes) ----------
__global__ void convert_w_k(const float* __restrict__ Wn1, const float* __restrict__ Wn2,
                            const float* __restrict__ gW1, const float* __restrict__ gW2,
                            const float* __restrict__ tW1, const float* __restrict__ tW2,
                            const float* __restrict__ rW1, u16* __restrict__ Wb) {
    int m = blockIdx.x;
    const float* src;
    if (m < 6)       src = Wn1 + (size_t)(m >> 1) * (2 * HD * HD) + (size_t)(m & 1) * (HD * HD);
    else if (m < 9)  src = Wn2 + (size_t)(m - 6) * HD * HD;
    else if (m < 12) src = gW1 + (size_t)(m - 9) * HD * HD;
    else if (m < 15) src = gW2 + (size_t)(m - 12) * HD * HD;
    else if (m < 18) src = tW1 + (size_t)(m - 15) * HD * HD;
    else if (m < 21) src = tW2 + (size_t)(m - 18) * HD * HD;
    else             src = rW1;
    int t = threadIdx.x;
    int lane = t & 63, nn = t >> 6;
    u16* dh = Wb + (size_t)m * (2 * PLANE);
    u16* dl = dh + PLANE;
    for (int c = 0; c < 4; ++c) {
        for (int hh = 0; hh < 2; ++hh) {
            int n = nn + hh * 4;
            int col = n * 16 + (lane & 15);
            int k0 = c * 32 + (lane >> 4) * 8;
            u32 hv[4], lv[4];
#pragma unroll
            for (int jj = 0; jj < 4; ++jj) {
                float wA = src[(size_t)(k0 + 2 * jj) * HD + col];
                float wB = src[(size_t)(k0 + 2 * jj + 1) * HD + col];
                u16 ha = bf16rn(wA), hb = bf16rn(wB);
                u16 la = bf16rn(wA - u2f((u32)ha << 16));
                u16 lb = bf16rn(wB - u2f((u32)hb << 16));
                hv[jj] = (u32)ha | ((u32)hb << 16);
                lv[jj] = (u32)la | ((u32)lb << 16);
            }
            size_t off = ((size_t)(c * 8 + n) * 64 + lane) * 8;
            *(uint4*)(dh + off) = make_uint4(hv[0], hv[1], hv[2], hv[3]);
            *(uint4*)(dl + off) = make_uint4(lv[0], lv[1], lv[2], lv[3]);
        }
    }
}

// ---------- gates lookup table ----------
__global__ void gate_table_k(const float* __restrict__ We1, const float* __restrict__ be1,
                             const float* __restrict__ We2, const float* __restrict__ be2,
                             float* __restrict__ gtab) {
    int row = blockIdx.x;
    int l = row / (NBIN + 1);
    int i = row % (NBIN + 1);
    int j = threadIdx.x;
    float d = (CUTOFFF / NBIN) * (float)i;
    __shared__ float h1[HD];
    const float* w1 = We1 + (size_t)l * 16 * HD;
    float acc = be1[l * HD + j];
#pragma unroll
    for (int k = 0; k < 16; ++k) {
        float dd = d - 0.25f * (float)k;
        float es = __builtin_amdgcn_exp2f(-dd * dd * 8.0f * 1.44269504088896341f);
        acc = fmaf(es, w1[k * HD + j], acc);
    }
    h1[j] = sspf(acc);
    __syncthreads();
    const float* w2 = We2 + (size_t)l * HD * HD;
    float acc2 = be2[l * HD + j];
    for (int k = 0; k < HD; ++k) acc2 = fmaf(h1[k], w2[k * HD + j], acc2);
    float sc = 1.f - sigf(5.f * (d - (CUTOFFF - 1.5f)));
    gtab[(size_t)row * HD + j] = acc2 * sc;
}

// ---------- CSR sort kernels ----------
__global__ __launch_bounds__(256) void hist_k(const int* __restrict__ pe, u32* __restrict__ cnt) {
    int e = blockIdx.x * 256 + threadIdx.x;
    if (e < NEDGE) atomic_add_u(&cnt[pe[2 * e + 1]], 1u);
}

__global__ __launch_bounds__(1024) void scan_k(const u32* __restrict__ cnt, u32* __restrict__ cur) {
    __shared__ u32 sums[1024];
    int t = threadIdx.x;
    const int CH = (NPROBE + 1023) / 1024;
    int lo = t * CH, hi = lo + CH;
    if (hi > NPROBE) hi = NPROBE;
    u32 s = 0;
    for (int i = lo; i < hi; ++i) s += cnt[i];
    sums[t] = s;
    __syncthreads();
    for (int d = 1; d < 1024; d <<= 1) {
        u32 v = (t >= d) ? sums[t - d] : 0u;
        __syncthreads();
        sums[t] += v;
        __syncthreads();
    }
    u32 base = (t == 0) ? 0u : sums[t - 1];
    for (int i = lo; i < hi; ++i) {
        cur[i] = base;
        base += cnt[i];
    }
}

__global__ __launch_bounds__(256) void scatter_k(const int* __restrict__ pe,
                                                 u32* __restrict__ cur, u32* __restrict__ eord) {
    int e = blockIdx.x * 256 + threadIdx.x;
    if (e < NEDGE) {
        u32 pos = atomic_add_u(&cur[pe[2 * e + 1]], 1u);
        eord[pos] = (u32)e;
    }
}

// ---------- atom projection: Xab[l] = atom_rep[l] @ Wn1_atom[l] + bn1[l] ----------
#define ABLK 313
__global__ __launch_bounds__(NT, 4) void gemm_atoms_k(const float* __restrict__ atom_rep,
                                                      const u16* __restrict__ Wb,
                                                      const float* __restrict__ bn1,
                                                      float* __restrict__ Xab) {
    __shared__ u16 ldsH[MT * 128];
    __shared__ u16 ldsL[MT * 128];
    int l = blockIdx.x / ABLK;
    int mb = blockIdx.x % ABLK;
    const float* A = atom_rep + (size_t)l * NATOM * HD;
    const u16* W = Wb + (size_t)(2 * l) * 2 * PLANE;
    float* outp = Xab + (size_t)l * NATOM * HD;
    int m0 = mb * MT, t = threadIdx.x;
    stage_split(A, NATOM, m0, t, ldsH, ldsL);
    __syncthreads();
    int lane = t & 63, wid = t >> 6;
    int l15 = lane & 15, lq = lane >> 4;
    int col = wid * 16 + l15;
    f32x4 acc[4] = {};
    mma_slice(ldsH, ldsL, lane, wid, W, acc);
    float bv = bn1[l * HD + col];
#pragma unroll
    for (int m = 0; m < 4; ++m) {
#pragma unroll
        for (int r = 0; r < 4; ++r) {
            int row = m0 + m * 16 + lq * 4 + r;
            if (row < NATOM) outp[(size_t)row * HD + col] = acc[m][r] + bv;
        }
    }
}

// ---------- edge kernel (receiver-sorted, weight-stationary) ----------
__global__ __launch_bounds__(NT, 4) void edge_msg_k(
        const float* __restrict__ Xab, const float* __restrict__ Xp,
        const u16* __restrict__ W2b, const float* __restrict__ bn2,
        const float* __restrict__ gtab, const float* __restrict__ dist,
        const int* __restrict__ pe, const u32* __restrict__ eord,
        float* __restrict__ msgsum) {
    __shared__ u16 ldsH[MT * 128];
    __shared__ u16 ldsL[MT * 128];
    __shared__ int rcv_s[MT];
    __shared__ float fr_s[MT];
    __shared__ int ib_s[MT];
    int e0 = blockIdx.x * MT;
    int t = threadIdx.x;
    if (t < MT) {
        int e = (int)eord[e0 + t];
        rcv_s[t] = pe[2 * e + 1];
        float x = dist[e] * ((float)NBIN / CUTOFFF);
        int i = (int)x;
        i = i < (NBIN - 1) ? i : (NBIN - 1);
        fr_s[t] = x - (float)i;
        ib_s[t] = i;
    }
    {
        int r = t >> 3, q = t & 7;
        int e = (int)eord[e0 + r];
        int snd = pe[2 * e], rcv = pe[2 * e + 1];
        const float4* xa = (const float4*)(Xab + (size_t)snd * HD + q * 16);
        const float4* xp = (const float4*)(Xp + (size_t)rcv * HD + q * 16);
        int s = r & 7;
#pragma unroll
        for (int j = 0; j < 4; ++j) {
            float4 va = xa[j], vp = xp[j];
            float h0 = sspf(va.x + vp.x), h1 = sspf(va.y + vp.y);
            float h2 = sspf(va.z + vp.z), h3 = sspf(va.w + vp.w);
            u32 a, b, c, d;
            split_pair(h0, h1, a, b);
            split_pair(h2, h3, c, d);
            int gc = q * 2 + (j >> 1);
            int off = r * 128 + ((gc ^ s) << 3) + (j & 1) * 4;
            *(uint2*)(ldsH + off) = make_uint2(a, c);
            *(uint2*)(ldsL + off) = make_uint2(b, d);
        }
    }
    __syncthreads();
    int lane = t & 63, wid = t >> 6;
    int l15 = lane & 15, lq = lane >> 4;
    int col = wid * 16 + l15;
    f32x4 acc[4] = {};
    mma_slice(ldsH, ldsL, lane, wid, W2b, acc);
    float bb = bn2[col];
#pragma unroll
    for (int m = 0; m < 4; ++m) {
        int rbase = m * 16 + lq * 4;
        float vals[4];
        int rc[4];
#pragma unroll
        for (int r = 0; r < 4; ++r) {
            int er = rbase + r;
            rc[r] = rcv_s[er];
            const float* gp = gtab + (size_t)ib_s[er] * HD;
            float ga = gp[col], gb = gp[HD + col];
            vals[r] = (acc[m][r] + bb) * fmaf(gb - ga, fr_s[er], ga);
        }
#pragma unroll
        for (int r = 3; r >= 1; --r) {
            if (rc[r] == rc[r - 1]) {
                vals[r - 1] += vals[r];
            } else {
                atomic_add_f(msgsum + (size_t)rc[r] * HD + col, vals[r]);
            }
        }
        atomic_add_f(msgsum + (size_t)rc[0] * HD + col, vals[0]);
    }
}

// ---------- fused probe update (+Xp projection or readout) ----------
__global__ __launch_bounds__(NT, 4) void probe_update_k(
        const float* ps, const float* __restrict__ msgsum,
        const u16* __restrict__ gW1b, const float* __restrict__ gb1,
        const u16* __restrict__ gW2b, const float* __restrict__ gb2,
        const u16* __restrict__ tW1b, const float* __restrict__ tb1,
        const u16* __restrict__ tW2b, const float* __restrict__ tb2,
        const u16* __restrict__ W3b,
        const u16* __restrict__ rW1b, const float* __restrict__ rb1,
        const float* __restrict__ rW2, const float* __restrict__ rb2,
        float* psout, float* __restrict__ xpout, float* __restrict__ outp) {
    __shared__ u16 ldsH[MT * 128];
    __shared__ u16 ldsL[MT * 128];
    __shared__ float parts[MT][9];
    int m0 = blockIdx.x * MT, t = threadIdx.x;
    int lane = t & 63, wid = t >> 6;
    int l15 = lane & 15, lq = lane >> 4;
    int col = wid * 16 + l15;

    // ---- gate path: g = sigmoid(MLP_g(ps)) ----
    stage_split(ps, NPROBE, m0, t, ldsH, ldsL);
    __syncthreads();
    f32x4 g[4] = {};
    mma_slice(ldsH, ldsL, lane, wid, gW1b, g);
    __syncthreads();
    h_store(ldsH, ldsL, wid, lane, g, gb1);
    __syncthreads();
#pragma unroll
    for (int m = 0; m < 4; ++m) g[m] = (f32x4){0.f, 0.f, 0.f, 0.f};
    mma_slice(ldsH, ldsL, lane, wid, gW2b, g);
    float gb2v = gb2[col];
#pragma unroll
    for (int m = 0; m < 4; ++m)
#pragma unroll
        for (int r = 0; r < 4; ++r) g[m][r] = sigf(g[m][r] + gb2v);
    __syncthreads();

    // ---- trans path: tv = MLP_t(msgsum) ----
    stage_split(msgsum, NPROBE, m0, t, ldsH, ldsL);
    __syncthreads();
    f32x4 tv[4] = {};
    mma_slice(ldsH, ldsL, lane, wid, tW1b, tv);
    __syncthreads();
    h_store(ldsH, ldsL, wid, lane, tv, tb1);
    __syncthreads();
#pragma unroll
    for (int m = 0; m < 4; ++m) tv[m] = (f32x4){0.f, 0.f, 0.f, 0.f};
    mma_slice(ldsH, ldsL, lane, wid, tW2b, tv);

    // ---- combine: ps_new = ps*g + (1-g)*t ----
    bool proj = (W3b != nullptr) || (rW1b != nullptr);
    if (proj) __syncthreads();
    float tb2v = tb2[col];
#pragma unroll
    for (int m = 0; m < 4; ++m) {
#pragma unroll
        for (int r = 0; r < 4; ++r) {
            int row = m0 + m * 16 + lq * 4 + r;
            float val = 0.f;
            if (row < NPROBE) {
                size_t idx = (size_t)row * HD + col;
                float tval = tv[m][r] + tb2v;
                val = fmaf(ps[idx] - tval, g[m][r], tval);
                psout[idx] = val;
            }
            if (proj) v_store(ldsH, ldsL, wid, lane, m, r, val);
        }
    }
    if (W3b) {
        __syncthreads();
        f32x4 a[4] = {};
        mma_slice(ldsH, ldsL, lane, wid, W3b, a);
#pragma unroll
        for (int m = 0; m < 4; ++m)
#pragma unroll
            for (int r = 0; r < 4; ++r) {
                int row = m0 + m * 16 + lq * 4 + r;
                if (row < NPROBE) xpout[(size_t)row * HD + col] = a[m][r];
            }
    } else if (rW1b) {
        __syncthreads();
        f32x4 a[4] = {};
        mma_slice(ldsH, ldsL, lane, wid, rW1b, a);
        float rb1v = rb1[col], w2v = rW2[col];
#pragma unroll
        for (int m = 0; m < 4; ++m)
#pragma unroll
            for (int r = 0; r < 4; ++r) {
                float p = sspf(a[m][r] + rb1v) * w2v;
                p += __shfl_xor(p, 1, 16);
                p += __shfl_xor(p, 2, 16);
                p += __shfl_xor(p, 4, 16);
                p += __shfl_xor(p, 8, 16);
                if (l15 == 0) parts[m * 16 + lq * 4 + r][wid] = p;
            }
        __syncthreads();
        if (t < MT) {
            int row = m0 + t;
            if (row < NPROBE) {
                float s = rb2[0];
#pragma unroll
                for (int w = 0; w < 8; ++w) s += parts[t][w];
                outp[row] = s;
            }
        }
    }
}

// ---------- launcher ----------
extern "C" void kernel_launch(void* const* d_in, const int* in_sizes, int n_in,
                              void* d_out, int out_size, void* d_ws, size_t ws_size,
                              hipStream_t stream) {
    const float* atom_rep = (const float*)d_in[0];
    const float* dist     = (const float*)d_in[1];
    const float* We1 = (const float*)d_in[2];
    const float* be1 = (const float*)d_in[3];
    const float* We2 = (const float*)d_in[4];
    const float* be2 = (const float*)d_in[5];
    const float* Wn1 = (const float*)d_in[6];
    const float* bn1 = (const float*)d_in[7];
    const float* Wn2 = (const float*)d_in[8];
    const float* bn2 = (const float*)d_in[9];
    const float* gW1 = (const float*)d_in[10];
    const float* gb1 = (const float*)d_in[11];
    const float* gW2 = (const float*)d_in[12];
    const float* gb2 = (const float*)d_in[13];
    const float* tW1 = (const float*)d_in[14];
    const float* tb1 = (const float*)d_in[15];
    const float* tW2 = (const float*)d_in[16];
    const float* tb2 = (const float*)d_in[17];
    const float* rW1 = (const float*)d_in[18];
    const float* rb1 = (const float*)d_in[19];
    const float* rW2 = (const float*)d_in[20];
    const float* rb2 = (const float*)d_in[21];
    const int*   pe  = (const int*)d_in[22];
    float* out = (float*)d_out;

    float* ws = (float*)d_ws;
    float* ps     = ws;                         // 12,800,000 f
    float* msgsum = ps + 12800000u;             // 12,800,000 f
    float* Xp     = msgsum + 12800000u;         // 12,800,000 f
    float* Xab    = Xp + 12800000u;             // 3 * 2,560,000 f (bias folded)
    float* gtab   = Xab + 7680000u;             // 786,816 f
    u16*   Wb     = (u16*)(gtab + 786816u);     // 22*2*PLANE u16
    u32*   cnt    = (u32*)(Wb + 22 * 2 * PLANE);
    u32*   cur    = cnt + NPROBE;
    u32*   eord   = cur + NPROBE;

    const int PBLK = (NPROBE + MT - 1) / MT;   // 1563
    const int EBLK = NEDGE / MT;               // 6250
    const int TBLK = (NEDGE + 255) / 256;      // 1563

    hipMemsetAsync(ps, 0, 12800000ull * 4, stream);
    hipMemsetAsync(Xp, 0, 12800000ull * 4, stream);
    hipMemsetAsync(cnt, 0, (size_t)NPROBE * 4, stream);
    convert_w_k<<<22, 256, 0, stream>>>(Wn1, Wn2, gW1, gW2, tW1, tW2, rW1, Wb);
    gate_table_k<<<NLAYER * (NBIN + 1), HD, 0, stream>>>(We1, be1, We2, be2, gtab);
    hist_k<<<TBLK, 256, 0, stream>>>(pe, cnt);
    scan_k<<<1, 1024, 0, stream>>>(cnt, cur);
    scatter_k<<<TBLK, 256, 0, stream>>>(pe, cur, eord);
    gemm_atoms_k<<<NLAYER * ABLK, NT, 0, stream>>>(atom_rep, Wb, bn1, Xab);

    for (int l = 0; l < NLAYER; ++l) {
        hipMemsetAsync(msgsum, 0, 12800000ull * 4, stream);
        edge_msg_k<<<EBLK, NT, 0, stream>>>(Xab + (size_t)l * NATOM * HD, Xp,
                                            Wb + (size_t)(6 + l) * 2 * PLANE,
                                            bn2 + l * HD,
                                            gtab + (size_t)l * (NBIN + 1) * HD,
                                            dist, pe, eord, msgsum);
        const u16* W3  = (l < NLAYER - 1) ? Wb + (size_t)(2 * (l + 1) + 1) * 2 * PLANE : nullptr;
        const u16* RW1 = (l == NLAYER - 1) ? Wb + (size_t)21 * 2 * PLANE : nullptr;
        probe_update_k<<<PBLK, NT, 0, stream>>>(ps, msgsum,
                                                Wb + (size_t)(9 + l) * 2 * PLANE, gb1 + l * HD,
                                                Wb + (size_t)(12 + l) * 2 * PLANE, gb2 + l * HD,
                                                Wb + (size_t)(15 + l) * 2 * PLANE, tb1 + l * HD,
                                                Wb + (size_t)(18 + l) * 2 * PLANE, tb2 + l * HD,
                                                W3, RW1, rb1, rW2, rb2,
                                                ps, Xp, out);
    }
}

// Round 6
// 781.409 us; speedup vs baseline: 1.8948x; 1.2643x over previous
//
#include <hip/hip_runtime.h>

#define NLAYER 3
#define NATOM 20000
#define NPROBE 100000
#define NEDGE 400000
#define HD 128
#define NBIN 2048
#define CUTOFFF 4.0f
#define PLANE 16384   // ushorts per bf16 plane (128x128)
#define MT 64         // row tile
#define NT 512        // threads per block (8 waves)
#define NSBLK ((NPROBE + 255) / 256)   // 391 scan blocks

typedef unsigned int u32;
typedef unsigned short u16;
typedef __attribute__((ext_vector_type(8))) short bf16x8;
typedef __attribute__((ext_vector_type(4))) float f32x4;

// ---------- math helpers ----------
__device__ __forceinline__ float sspf(float x) {
    float e = __builtin_amdgcn_exp2f(fminf(x, 80.f) * 1.44269504088896341f);
    return 0.69314718055994531f * (__builtin_amdgcn_logf(1.f + e) - 1.f);
}
__device__ __forceinline__ float sigf(float x) {
    return 1.f / (1.f + __builtin_amdgcn_exp2f(-x * 1.44269504088896341f));
}
__device__ __forceinline__ void atomic_add_f(float* p, float v) {
    __hip_atomic_fetch_add(p, v, __ATOMIC_RELAXED, __HIP_MEMORY_SCOPE_AGENT);
}
__device__ __forceinline__ u32 atomic_add_u(u32* p, u32 v) {
    return __hip_atomic_fetch_add(p, v, __ATOMIC_RELAXED, __HIP_MEMORY_SCOPE_AGENT);
}
__device__ __forceinline__ u32 f2u(float f) { union { float f; u32 u; } x; x.f = f; return x.u; }
__device__ __forceinline__ float u2f(u32 u) { union { float f; u32 u; } x; x.u = u; return x.f; }
__device__ __forceinline__ u16 bf16rn(float f) {
    u32 u = f2u(f);
    u32 r = u + 0x7fffu + ((u >> 16) & 1u);
    return (u16)(r >> 16);
}
__device__ __forceinline__ void split_pair(float x, float y, u32& hi, u32& lo) {
    u32 ux = f2u(x);
    u32 hx = (ux + 0x7fffu + ((ux >> 16) & 1u)) & 0xffff0000u;
    float lxf = x - u2f(hx);
    u32 uy = f2u(y);
    u32 hy = (uy + 0x7fffu + ((uy >> 16) & 1u)) & 0xffff0000u;
    float lyf = y - u2f(hy);
    hi = (hx >> 16) | hy;
    lo = (f2u(lxf) >> 16) | (f2u(lyf) & 0xffff0000u);
}

// ---------- MFMA core: weight-stationary column slice ----------
__device__ __forceinline__ void mma_slice(const u16* __restrict__ ldsH,
                                          const u16* __restrict__ ldsL,
                                          int lane, int wid,
                                          const u16* __restrict__ Wb,
                                          f32x4 acc[4]) {
    const bf16x8* Bhp = (const bf16x8*)Wb;
    const bf16x8* Blp = (const bf16x8*)(Wb + PLANE);
    bf16x8 Bh[4], Bl[4];
#pragma unroll
    for (int c = 0; c < 4; ++c) {
        Bh[c] = Bhp[(size_t)(c * 8 + wid) * 64 + lane];
        Bl[c] = Blp[(size_t)(c * 8 + wid) * 64 + lane];
    }
    int l15 = lane & 15, kq = lane >> 4;
#pragma unroll
    for (int m = 0; m < 4; ++m) {
        int row = m * 16 + l15;
        int s = row & 7;
        const u16* hp = ldsH + row * 128;
        const u16* lp = ldsL + row * 128;
#pragma unroll
        for (int c = 0; c < 4; ++c) {
            int off = ((c * 4 + kq) ^ s) << 3;
            bf16x8 Ah = *(const bf16x8*)(hp + off);
            bf16x8 Al = *(const bf16x8*)(lp + off);
            acc[m] = __builtin_amdgcn_mfma_f32_16x16x32_bf16(Ah, Bh[c], acc[m], 0, 0, 0);
            acc[m] = __builtin_amdgcn_mfma_f32_16x16x32_bf16(Al, Bh[c], acc[m], 0, 0, 0);
            acc[m] = __builtin_amdgcn_mfma_f32_16x16x32_bf16(Ah, Bl[c], acc[m], 0, 0, 0);
        }
    }
}

__device__ __forceinline__ void stage_split(const float* __restrict__ A, int M,
                                            int m0, int t, u16* ldsH, u16* ldsL) {
    int r = t >> 3, q = t & 7;
    int row = m0 + r;
    bool ok = row < M;
    const float4* src = (const float4*)(A + (size_t)row * HD + q * 16);
    int s = r & 7;
#pragma unroll
    for (int j = 0; j < 4; ++j) {
        float4 v = ok ? src[j] : make_float4(0.f, 0.f, 0.f, 0.f);
        u32 h0, l0, h1, l1;
        split_pair(v.x, v.y, h0, l0);
        split_pair(v.z, v.w, h1, l1);
        int gc = q * 2 + (j >> 1);
        int off = r * 128 + ((gc ^ s) << 3) + (j & 1) * 4;
        *(uint2*)(ldsH + off) = make_uint2(h0, h1);
        *(uint2*)(ldsL + off) = make_uint2(l0, l1);
    }
}

__device__ __forceinline__ void h_store(u16* ldsH, u16* ldsL, int wid, int lane,
                                        const f32x4 acc[4], const float* __restrict__ bias) {
    int l15 = lane & 15, lq = lane >> 4;
    int col = wid * 16 + l15;
    float bb = bias[col];
    int gc = col >> 3, wg = col & 7;
#pragma unroll
    for (int m = 0; m < 4; ++m) {
#pragma unroll
        for (int r = 0; r < 4; ++r) {
            int row = m * 16 + lq * 4 + r;
            float h = sspf(acc[m][r] + bb);
            u32 u = f2u(h);
            u32 hh = (u + 0x7fffu + ((u >> 16) & 1u)) & 0xffff0000u;
            float lf = h - u2f(hh);
            int off = row * 128 + ((gc ^ (row & 7)) << 3) + wg;
            ldsH[off] = (u16)(hh >> 16);
            ldsL[off] = (u16)(f2u(lf) >> 16);
        }
    }
}

__device__ __forceinline__ void v_store(u16* ldsH, u16* ldsL, int wid, int lane,
                                        int m, int r, float val) {
    int l15 = lane & 15, lq = lane >> 4;
    int col = wid * 16 + l15;
    int gc = col >> 3, wg = col & 7;
    int row = m * 16 + lq * 4 + r;
    u32 u = f2u(val);
    u32 hh = (u + 0x7fffu + ((u >> 16) & 1u)) & 0xffff0000u;
    float lf = val - u2f(hh);
    int off = row * 128 + ((gc ^ (row & 7)) << 3) + wg;
    ldsH[off] = (u16)(hh >> 16);
    ldsL[off] = (u16)(f2u(lf) >> 16);
}

// ---------- weight conversion ----------
__global__ void convert_w_k(const float* __restrict__ Wn1, const float* __restrict__ Wn2,
                            const float* __restrict__ gW1, const float* __restrict__ gW2,
                            const float* __restrict__ tW1, const float* __restrict__ tW2,
                            const float* __restrict__ rW1, u16* __restrict__ Wb) {
    int m = blockIdx.x;
    const float* src;
    if (m < 6)       src = Wn1 + (size_t)(m >> 1) * (2 * HD * HD) + (size_t)(m & 1) * (HD * HD);
    else if (m < 9)  src = Wn2 + (size_t)(m - 6) * HD * HD;
    else if (m < 12) src = gW1 + (size_t)(m - 9) * HD * HD;
    else if (m < 15) src = gW2 + (size_t)(m - 12) * HD * HD;
    else if (m < 18) src = tW1 + (size_t)(m - 15) * HD * HD;
    else if (m < 21) src = tW2 + (size_t)(m - 18) * HD * HD;
    else             src = rW1;
    int t = threadIdx.x;
    int lane = t & 63, nn = t >> 6;
    u16* dh = Wb + (size_t)m * (2 * PLANE);
    u16* dl = dh + PLANE;
    for (int c = 0; c < 4; ++c) {
        for (int hh = 0; hh < 2; ++hh) {
            int n = nn + hh * 4;
            int col = n * 16 + (lane & 15);
            int k0 = c * 32 + (lane >> 4) * 8;
            u32 hv[4], lv[4];
#pragma unroll
            for (int jj = 0; jj < 4; ++jj) {
                float wA = src[(size_t)(k0 + 2 * jj) * HD + col];
                float wB = src[(size_t)(k0 + 2 * jj + 1) * HD + col];
                u16 ha = bf16rn(wA), hb = bf16rn(wB);
                u16 la = bf16rn(wA - u2f((u32)ha << 16));
                u16 lb = bf16rn(wB - u2f((u32)hb << 16));
                hv[jj] = (u32)ha | ((u32)hb << 16);
                lv[jj] = (u32)la | ((u32)lb << 16);
            }
            size_t off = ((size_t)(c * 8 + n) * 64 + lane) * 8;
            *(uint4*)(dh + off) = make_uint4(hv[0], hv[1], hv[2], hv[3]);
            *(uint4*)(dl + off) = make_uint4(lv[0], lv[1], lv[2], lv[3]);
        }
    }
}

// ---------- gates lookup table ----------
__global__ void gate_table_k(const float* __restrict__ We1, const float* __restrict__ be1,
                             const float* __restrict__ We2, const float* __restrict__ be2,
                             float* __restrict__ gtab) {
    int row = blockIdx.x;
    int l = row / (NBIN + 1);
    int i = row % (NBIN + 1);
    int j = threadIdx.x;
    float d = (CUTOFFF / NBIN) * (float)i;
    __shared__ float h1[HD];
    const float* w1 = We1 + (size_t)l * 16 * HD;
    float acc = be1[l * HD + j];
#pragma unroll
    for (int k = 0; k < 16; ++k) {
        float dd = d - 0.25f * (float)k;
        float es = __builtin_amdgcn_exp2f(-dd * dd * 8.0f * 1.44269504088896341f);
        acc = fmaf(es, w1[k * HD + j], acc);
    }
    h1[j] = sspf(acc);
    __syncthreads();
    const float* w2 = We2 + (size_t)l * HD * HD;
    float acc2 = be2[l * HD + j];
    for (int k = 0; k < HD; ++k) acc2 = fmaf(h1[k], w2[k * HD + j], acc2);
    float sc = 1.f - sigf(5.f * (d - (CUTOFFF - 1.5f)));
    gtab[(size_t)row * HD + j] = acc2 * sc;
}

// ---------- layer-0 constant gate: g0 = sigmoid(ssp(gb1)@gW2 + gb2) ----------
__global__ void gate0_k(const float* __restrict__ gW2, const float* __restrict__ gb1,
                        const float* __restrict__ gb2, float* __restrict__ g0v) {
    int j = threadIdx.x;
    __shared__ float h[HD];
    h[j] = sspf(gb1[j]);
    __syncthreads();
    float acc = gb2[j];
    for (int k = 0; k < HD; ++k) acc = fmaf(h[k], gW2[k * HD + j], acc);
    g0v[j] = sigf(acc);
}

// ---------- CSR sort ----------
__global__ __launch_bounds__(256) void hist_k(const int* __restrict__ pe, u32* __restrict__ cnt) {
    int e = blockIdx.x * 256 + threadIdx.x;
    if (e < NEDGE) atomic_add_u(&cnt[pe[2 * e + 1]], 1u);
}

// partial sums: bsum[b] = sum cnt[b*256 .. +255]
__global__ __launch_bounds__(256) void bsum_k(const u32* __restrict__ cnt, u32* __restrict__ bsum) {
    int i = blockIdx.x * 256 + threadIdx.x;
    int v = (i < NPROBE) ? (int)cnt[i] : 0;
#pragma unroll
    for (int d = 1; d < 64; d <<= 1) v += __shfl_xor(v, d);
    __shared__ int wsum[4];
    if ((threadIdx.x & 63) == 0) wsum[threadIdx.x >> 6] = v;
    __syncthreads();
    if (threadIdx.x == 0) bsum[blockIdx.x] = (u32)(wsum[0] + wsum[1] + wsum[2] + wsum[3]);
}

// single-block exclusive scan of NSBLK block sums (in place)
__global__ __launch_bounds__(512) void bscan_k(u32* __restrict__ bsum) {
    __shared__ u32 s[512];
    int t = threadIdx.x;
    u32 v = (t < NSBLK) ? bsum[t] : 0u;
    s[t] = v;
    __syncthreads();
    for (int d = 1; d < 512; d <<= 1) {
        u32 x = (t >= d) ? s[t - d] : 0u;
        __syncthreads();
        s[t] += x;
        __syncthreads();
    }
    if (t < NSBLK) bsum[t] = s[t] - v;   // exclusive
}

// cur[i] = bsum[b] + local exclusive scan
__global__ __launch_bounds__(256) void cur_k(const u32* __restrict__ cnt,
                                             const u32* __restrict__ bsum, u32* __restrict__ cur) {
    __shared__ u32 s[256];
    int b = blockIdx.x, t = threadIdx.x;
    int i = b * 256 + t;
    u32 v = (i < NPROBE) ? cnt[i] : 0u;
    s[t] = v;
    __syncthreads();
    for (int d = 1; d < 256; d <<= 1) {
        u32 x = (t >= d) ? s[t - d] : 0u;
        __syncthreads();
        s[t] += x;
        __syncthreads();
    }
    if (i < NPROBE) cur[i] = bsum[b] + s[t] - v;
}

__global__ __launch_bounds__(256) void scatter_k(const int* __restrict__ pe,
                                                 u32* __restrict__ cur, u32* __restrict__ eord) {
    int e = blockIdx.x * 256 + threadIdx.x;
    if (e < NEDGE) {
        u32 pos = atomic_add_u(&cur[pe[2 * e + 1]], 1u);
        eord[pos] = (u32)e;
    }
}

// ---------- atom projection: Xab[l] = atom_rep[l] @ Wn1_atom[l] + bn1[l] ----------
#define ABLK 313
__global__ __launch_bounds__(NT, 4) void gemm_atoms_k(const float* __restrict__ atom_rep,
                                                      const u16* __restrict__ Wb,
                                                      const float* __restrict__ bn1,
                                                      float* __restrict__ Xab) {
    __shared__ u16 ldsH[MT * 128];
    __shared__ u16 ldsL[MT * 128];
    int l = blockIdx.x / ABLK;
    int mb = blockIdx.x % ABLK;
    const float* A = atom_rep + (size_t)l * NATOM * HD;
    const u16* W = Wb + (size_t)(2 * l) * 2 * PLANE;
    float* outp = Xab + (size_t)l * NATOM * HD;
    int m0 = mb * MT, t = threadIdx.x;
    stage_split(A, NATOM, m0, t, ldsH, ldsL);
    __syncthreads();
    int lane = t & 63, wid = t >> 6;
    int l15 = lane & 15, lq = lane >> 4;
    int col = wid * 16 + l15;
    f32x4 acc[4] = {};
    mma_slice(ldsH, ldsL, lane, wid, W, acc);
    float bv = bn1[l * HD + col];
#pragma unroll
    for (int m = 0; m < 4; ++m) {
#pragma unroll
        for (int r = 0; r < 4; ++r) {
            int row = m0 + m * 16 + lq * 4 + r;
            if (row < NATOM) outp[(size_t)row * HD + col] = acc[m][r] + bv;
        }
    }
}

// ---------- edge kernel (receiver-sorted, weight-stationary; Xp==null => layer0) ----------
__global__ __launch_bounds__(NT, 4) void edge_msg_k(
        const float* __restrict__ Xab, const float* __restrict__ Xp,
        const u16* __restrict__ W2b, const float* __restrict__ bn2,
        const float* __restrict__ gtab, const float* __restrict__ dist,
        const int* __restrict__ pe, const u32* __restrict__ eord,
        float* __restrict__ msgsum) {
    __shared__ u16 ldsH[MT * 128];
    __shared__ u16 ldsL[MT * 128];
    __shared__ int rcv_s[MT];
    __shared__ float fr_s[MT];
    __shared__ int ib_s[MT];
    int e0 = blockIdx.x * MT;
    int t = threadIdx.x;
    if (t < MT) {
        int e = (int)eord[e0 + t];
        rcv_s[t] = pe[2 * e + 1];
        float x = dist[e] * ((float)NBIN / CUTOFFF);
        int i = (int)x;
        i = i < (NBIN - 1) ? i : (NBIN - 1);
        fr_s[t] = x - (float)i;
        ib_s[t] = i;
    }
    {
        int r = t >> 3, q = t & 7;
        int e = (int)eord[e0 + r];
        int snd = pe[2 * e], rcv = pe[2 * e + 1];
        const float4* xa = (const float4*)(Xab + (size_t)snd * HD + q * 16);
        const float4* xp = Xp ? (const float4*)(Xp + (size_t)rcv * HD + q * 16) : nullptr;
        int s = r & 7;
#pragma unroll
        for (int j = 0; j < 4; ++j) {
            float4 va = xa[j];
            if (xp) {
                float4 vp = xp[j];
                va.x += vp.x; va.y += vp.y; va.z += vp.z; va.w += vp.w;
            }
            float h0 = sspf(va.x), h1 = sspf(va.y), h2 = sspf(va.z), h3 = sspf(va.w);
            u32 a, b, c, d;
            split_pair(h0, h1, a, b);
            split_pair(h2, h3, c, d);
            int gc = q * 2 + (j >> 1);
            int off = r * 128 + ((gc ^ s) << 3) + (j & 1) * 4;
            *(uint2*)(ldsH + off) = make_uint2(a, c);
            *(uint2*)(ldsL + off) = make_uint2(b, d);
        }
    }
    __syncthreads();
    int lane = t & 63, wid = t >> 6;
    int l15 = lane & 15, lq = lane >> 4;
    int col = wid * 16 + l15;
    f32x4 acc[4] = {};
    mma_slice(ldsH, ldsL, lane, wid, W2b, acc);
    float bb = bn2[col];
#pragma unroll
    for (int m = 0; m < 4; ++m) {
        int rbase = m * 16 + lq * 4;
        float vals[4];
        int rc[4];
#pragma unroll
        for (int r = 0; r < 4; ++r) {
            int er = rbase + r;
            rc[r] = rcv_s[er];
            const float* gp = gtab + (size_t)ib_s[er] * HD;
            float ga = gp[col], gb = gp[HD + col];
            vals[r] = (acc[m][r] + bb) * fmaf(gb - ga, fr_s[er], ga);
        }
#pragma unroll
        for (int r = 3; r >= 1; --r) {
            if (rc[r] == rc[r - 1]) {
                vals[r - 1] += vals[r];
            } else {
                atomic_add_f(msgsum + (size_t)rc[r] * HD + col, vals[r]);
            }
        }
        atomic_add_f(msgsum + (size_t)rc[0] * HD + col, vals[0]);
    }
}

// ---------- fused probe update (+Xp projection or readout) ----------
// g0v != nullptr => layer 0: gate = const g0v, ps treated as 0 (no gate MLP, no ps read)
__global__ __launch_bounds__(NT, 4) void probe_update_k(
        const float* ps, const float* __restrict__ msgsum,
        const u16* __restrict__ gW1b, const float* __restrict__ gb1,
        const u16* __restrict__ gW2b, const float* __restrict__ gb2,
        const u16* __restrict__ tW1b, const float* __restrict__ tb1,
        const u16* __restrict__ tW2b, const float* __restrict__ tb2,
        const u16* __restrict__ W3b,
        const u16* __restrict__ rW1b, const float* __restrict__ rb1,
        const float* __restrict__ rW2, const float* __restrict__ rb2,
        const float* __restrict__ g0v,
        float* psout, float* __restrict__ xpout, float* __restrict__ outp) {
    __shared__ u16 ldsH[MT * 128];
    __shared__ u16 ldsL[MT * 128];
    __shared__ float parts[MT][9];
    int m0 = blockIdx.x * MT, t = threadIdx.x;
    int lane = t & 63, wid = t >> 6;
    int l15 = lane & 15, lq = lane >> 4;
    int col = wid * 16 + l15;

    // ---- gate path ----
    f32x4 g[4] = {};
    if (!g0v) {
        stage_split(ps, NPROBE, m0, t, ldsH, ldsL);
        __syncthreads();
        mma_slice(ldsH, ldsL, lane, wid, gW1b, g);
        __syncthreads();
        h_store(ldsH, ldsL, wid, lane, g, gb1);
        __syncthreads();
#pragma unroll
        for (int m = 0; m < 4; ++m) g[m] = (f32x4){0.f, 0.f, 0.f, 0.f};
        mma_slice(ldsH, ldsL, lane, wid, gW2b, g);
        float gb2v = gb2[col];
#pragma unroll
        for (int m = 0; m < 4; ++m)
#pragma unroll
            for (int r = 0; r < 4; ++r) g[m][r] = sigf(g[m][r] + gb2v);
        __syncthreads();
    } else {
        float gv = g0v[col];
#pragma unroll
        for (int m = 0; m < 4; ++m)
#pragma unroll
            for (int r = 0; r < 4; ++r) g[m][r] = gv;
    }

    // ---- trans path: tv = MLP_t(msgsum) ----
    stage_split(msgsum, NPROBE, m0, t, ldsH, ldsL);
    __syncthreads();
    f32x4 tv[4] = {};
    mma_slice(ldsH, ldsL, lane, wid, tW1b, tv);
    __syncthreads();
    h_store(ldsH, ldsL, wid, lane, tv, tb1);
    __syncthreads();
#pragma unroll
    for (int m = 0; m < 4; ++m) tv[m] = (f32x4){0.f, 0.f, 0.f, 0.f};
    mma_slice(ldsH, ldsL, lane, wid, tW2b, tv);

    // ---- combine: ps_new = ps*g + (1-g)*t ----
    bool proj = (W3b != nullptr) || (rW1b != nullptr);
    if (proj) __syncthreads();
    float tb2v = tb2[col];
#pragma unroll
    for (int m = 0; m < 4; ++m) {
#pragma unroll
        for (int r = 0; r < 4; ++r) {
            int row = m0 + m * 16 + lq * 4 + r;
            float val = 0.f;
            if (row < NPROBE) {
                size_t idx = (size_t)row * HD + col;
                float tval = tv[m][r] + tb2v;
                float pv = g0v ? 0.f : ps[idx];
                val = fmaf(pv - tval, g[m][r], tval);
                if (!rW1b) psout[idx] = val;
            }
            if (proj) v_store(ldsH, ldsL, wid, lane, m, r, val);
        }
    }
    if (W3b) {
        __syncthreads();
        f32x4 a[4] = {};
        mma_slice(ldsH, ldsL, lane, wid, W3b, a);
#pragma unroll
        for (int m = 0; m < 4; ++m)
#pragma unroll
            for (int r = 0; r < 4; ++r) {
                int row = m0 + m * 16 + lq * 4 + r;
                if (row < NPROBE) xpout[(size_t)row * HD + col] = a[m][r];
            }
    } else if (rW1b) {
        __syncthreads();
        f32x4 a[4] = {};
        mma_slice(ldsH, ldsL, lane, wid, rW1b, a);
        float rb1v = rb1[col], w2v = rW2[col];
#pragma unroll
        for (int m = 0; m < 4; ++m)
#pragma unroll
            for (int r = 0; r < 4; ++r) {
                float p = sspf(a[m][r] + rb1v) * w2v;
                p += __shfl_xor(p, 1, 16);
                p += __shfl_xor(p, 2, 16);
                p += __shfl_xor(p, 4, 16);
                p += __shfl_xor(p, 8, 16);
                if (l15 == 0) parts[m * 16 + lq * 4 + r][wid] = p;
            }
        __syncthreads();
        if (t < MT) {
            int row = m0 + t;
            if (row < NPROBE) {
                float s = rb2[0];
#pragma unroll
                for (int w = 0; w < 8; ++w) s += parts[t][w];
                outp[row] = s;
            }
        }
    }
}

// ---------- launcher ----------
extern "C" void kernel_launch(void* const* d_in, const int* in_sizes, int n_in,
                              void* d_out, int out_size, void* d_ws, size_t ws_size,
                              hipStream_t stream) {
    const float* atom_rep = (const float*)d_in[0];
    const float* dist     = (const float*)d_in[1];
    const float* We1 = (const float*)d_in[2];
    const float* be1 = (const float*)d_in[3];
    const float* We2 = (const float*)d_in[4];
    const float* be2 = (const float*)d_in[5];
    const float* Wn1 = (const float*)d_in[6];
    const float* bn1 = (const float*)d_in[7];
    const float* Wn2 = (const float*)d_in[8];
    const float* bn2 = (const float*)d_in[9];
    const float* gW1 = (const float*)d_in[10];
    const float* gb1 = (const float*)d_in[11];
    const float* gW2 = (const float*)d_in[12];
    const float* gb2 = (const float*)d_in[13];
    const float* tW1 = (const float*)d_in[14];
    const float* tb1 = (const float*)d_in[15];
    const float* tW2 = (const float*)d_in[16];
    const float* tb2 = (const float*)d_in[17];
    const float* rW1 = (const float*)d_in[18];
    const float* rb1 = (const float*)d_in[19];
    const float* rW2 = (const float*)d_in[20];
    const float* rb2 = (const float*)d_in[21];
    const int*   pe  = (const int*)d_in[22];
    float* out = (float*)d_out;

    float* ws = (float*)d_ws;
    float* ps     = ws;                         // 12,800,000 f
    float* msgsum = ps + 12800000u;             // 12,800,000 f
    float* Xp     = msgsum + 12800000u;         // 12,800,000 f
    float* Xab    = Xp + 12800000u;             // 3 * 2,560,000 f
    float* gtab   = Xab + 7680000u;             // 786,816 f
    float* g0v    = gtab + 786816u;             // 128 f
    u16*   Wb     = (u16*)(g0v + 128);          // 22*2*PLANE u16
    u32*   cnt    = (u32*)(Wb + 22 * 2 * PLANE);
    u32*   bsum   = cnt + NPROBE;               // NSBLK
    u32*   cur    = bsum + 512;
    u32*   eord   = cur + NPROBE;

    const int PBLK = (NPROBE + MT - 1) / MT;   // 1563
    const int EBLK = NEDGE / MT;               // 6250
    const int TBLK = (NEDGE + 255) / 256;      // 1563

    hipMemsetAsync(cnt, 0, (size_t)NPROBE * 4, stream);
    convert_w_k<<<22, 256, 0, stream>>>(Wn1, Wn2, gW1, gW2, tW1, tW2, rW1, Wb);
    gate_table_k<<<NLAYER * (NBIN + 1), HD, 0, stream>>>(We1, be1, We2, be2, gtab);
    gate0_k<<<1, HD, 0, stream>>>(gW2, gb1, gb2, g0v);
    hist_k<<<TBLK, 256, 0, stream>>>(pe, cnt);
    bsum_k<<<NSBLK, 256, 0, stream>>>(cnt, bsum);
    bscan_k<<<1, 512, 0, stream>>>(bsum);
    cur_k<<<NSBLK, 256, 0, stream>>>(cnt, bsum, cur);
    scatter_k<<<TBLK, 256, 0, stream>>>(pe, cur, eord);
    gemm_atoms_k<<<NLAYER * ABLK, NT, 0, stream>>>(atom_rep, Wb, bn1, Xab);

    for (int l = 0; l < NLAYER; ++l) {
        hipMemsetAsync(msgsum, 0, 12800000ull * 4, stream);
        edge_msg_k<<<EBLK, NT, 0, stream>>>(Xab + (size_t)l * NATOM * HD,
                                            (l == 0) ? nullptr : Xp,
                                            Wb + (size_t)(6 + l) * 2 * PLANE,
                                            bn2 + l * HD,
                                            gtab + (size_t)l * (NBIN + 1) * HD,
                                            dist, pe, eord, msgsum);
        const u16* W3  = (l < NLAYER - 1) ? Wb + (size_t)(2 * (l + 1) + 1) * 2 * PLANE : nullptr;
        const u16* RW1 = (l == NLAYER - 1) ? Wb + (size_t)21 * 2 * PLANE : nullptr;
        probe_update_k<<<PBLK, NT, 0, stream>>>(ps, msgsum,
                                                Wb + (size_t)(9 + l) * 2 * PLANE, gb1 + l * HD,
                                                Wb + (size_t)(12 + l) * 2 * PLANE, gb2 + l * HD,
                                                Wb + (size_t)(15 + l) * 2 * PLANE, tb1 + l * HD,
                                                Wb + (size_t)(18 + l) * 2 * PLANE, tb2 + l * HD,
                                                W3, RW1, rb1, rW2, rb2,
                                                (l == 0) ? g0v : nullptr,
                                                ps, Xp, out);
    }
}

// Round 7
// 778.983 us; speedup vs baseline: 1.9007x; 1.0031x over previous
//
#include <hip/hip_runtime.h>

#define NLAYER 3
#define NATOM 20000
#define NPROBE 100000
#define NEDGE 400000
#define HD 128
#define NBIN 2048
#define CUTOFFF 4.0f
#define PLANE 16384   // ushorts per bf16 plane (128x128)
#define MT 64         // row tile
#define NT 512        // threads per block (8 waves)
#define NSBLK ((NPROBE + 255) / 256)   // 391 scan blocks

typedef unsigned int u32;
typedef unsigned short u16;
typedef __attribute__((ext_vector_type(8))) short bf16x8;
typedef __attribute__((ext_vector_type(4))) float f32x4;

// ---------- math helpers ----------
__device__ __forceinline__ float sspf(float x) {
    float e = __builtin_amdgcn_exp2f(fminf(x, 80.f) * 1.44269504088896341f);
    return 0.69314718055994531f * (__builtin_amdgcn_logf(1.f + e) - 1.f);
}
__device__ __forceinline__ float sigf(float x) {
    return 1.f / (1.f + __builtin_amdgcn_exp2f(-x * 1.44269504088896341f));
}
__device__ __forceinline__ void atomic_add_f(float* p, float v) {
    __hip_atomic_fetch_add(p, v, __ATOMIC_RELAXED, __HIP_MEMORY_SCOPE_AGENT);
}
__device__ __forceinline__ u32 atomic_add_u(u32* p, u32 v) {
    return __hip_atomic_fetch_add(p, v, __ATOMIC_RELAXED, __HIP_MEMORY_SCOPE_AGENT);
}
__device__ __forceinline__ u32 f2u(float f) { union { float f; u32 u; } x; x.f = f; return x.u; }
__device__ __forceinline__ float u2f(u32 u) { union { float f; u32 u; } x; x.u = u; return x.f; }
__device__ __forceinline__ u16 bf16rn(float f) {
    u32 u = f2u(f);
    u32 r = u + 0x7fffu + ((u >> 16) & 1u);
    return (u16)(r >> 16);
}
__device__ __forceinline__ void split_pair(float x, float y, u32& hi, u32& lo) {
    u32 ux = f2u(x);
    u32 hx = (ux + 0x7fffu + ((ux >> 16) & 1u)) & 0xffff0000u;
    float lxf = x - u2f(hx);
    u32 uy = f2u(y);
    u32 hy = (uy + 0x7fffu + ((uy >> 16) & 1u)) & 0xffff0000u;
    float lyf = y - u2f(hy);
    hi = (hx >> 16) | hy;
    lo = (f2u(lxf) >> 16) | (f2u(lyf) & 0xffff0000u);
}

// LDS-only barrier: do NOT drain vmcnt (atomics / prefetch loads stay in flight).
__device__ __forceinline__ void bar_lds() {
    asm volatile("s_waitcnt lgkmcnt(0)" ::: "memory");
    __builtin_amdgcn_s_barrier();
}

// ---------- MFMA core: weight-stationary column slice ----------
__device__ __forceinline__ void load_bfrags(const u16* __restrict__ Wb, int lane, int wid,
                                            bf16x8 Bh[4], bf16x8 Bl[4]) {
    const bf16x8* Bhp = (const bf16x8*)Wb;
    const bf16x8* Blp = (const bf16x8*)(Wb + PLANE);
#pragma unroll
    for (int c = 0; c < 4; ++c) {
        Bh[c] = Bhp[(size_t)(c * 8 + wid) * 64 + lane];
        Bl[c] = Blp[(size_t)(c * 8 + wid) * 64 + lane];
    }
}

__device__ __forceinline__ void mma_slice_pre(const u16* __restrict__ ldsH,
                                              const u16* __restrict__ ldsL,
                                              int lane, const bf16x8 Bh[4], const bf16x8 Bl[4],
                                              f32x4 acc[4]) {
    int l15 = lane & 15, kq = lane >> 4;
#pragma unroll
    for (int m = 0; m < 4; ++m) {
        int row = m * 16 + l15;
        int s = row & 7;
        const u16* hp = ldsH + row * 128;
        const u16* lp = ldsL + row * 128;
#pragma unroll
        for (int c = 0; c < 4; ++c) {
            int off = ((c * 4 + kq) ^ s) << 3;
            bf16x8 Ah = *(const bf16x8*)(hp + off);
            bf16x8 Al = *(const bf16x8*)(lp + off);
            acc[m] = __builtin_amdgcn_mfma_f32_16x16x32_bf16(Ah, Bh[c], acc[m], 0, 0, 0);
            acc[m] = __builtin_amdgcn_mfma_f32_16x16x32_bf16(Al, Bh[c], acc[m], 0, 0, 0);
            acc[m] = __builtin_amdgcn_mfma_f32_16x16x32_bf16(Ah, Bl[c], acc[m], 0, 0, 0);
        }
    }
}

__device__ __forceinline__ void mma_slice(const u16* __restrict__ ldsH,
                                          const u16* __restrict__ ldsL,
                                          int lane, int wid,
                                          const u16* __restrict__ Wb,
                                          f32x4 acc[4]) {
    bf16x8 Bh[4], Bl[4];
    load_bfrags(Wb, lane, wid, Bh, Bl);
    mma_slice_pre(ldsH, ldsL, lane, Bh, Bl, acc);
}

// ---------- staging helpers (row r = t>>3, 16-col chunk q = t&7) ----------
__device__ __forceinline__ void gather_rows(const float* __restrict__ A, int M,
                                            int m0, int t, float* v) {
    int r = t >> 3, q = t & 7;
    int row = m0 + r;
    bool ok = row < M;
    const float4* src = (const float4*)(A + (size_t)row * HD + q * 16);
#pragma unroll
    for (int j = 0; j < 4; ++j) {
        float4 x = ok ? src[j] : make_float4(0.f, 0.f, 0.f, 0.f);
        v[4 * j] = x.x; v[4 * j + 1] = x.y; v[4 * j + 2] = x.z; v[4 * j + 3] = x.w;
    }
}
__device__ __forceinline__ void pack_raw(const float* v, int t, u16* ldsH, u16* ldsL) {
    int r = t >> 3, q = t & 7;
    int s = r & 7;
#pragma unroll
    for (int j = 0; j < 4; ++j) {
        u32 a, b, c, d;
        split_pair(v[4 * j], v[4 * j + 1], a, b);
        split_pair(v[4 * j + 2], v[4 * j + 3], c, d);
        int gc = q * 2 + (j >> 1);
        int off = r * 128 + ((gc ^ s) << 3) + (j & 1) * 4;
        *(uint2*)(ldsH + off) = make_uint2(a, c);
        *(uint2*)(ldsL + off) = make_uint2(b, d);
    }
}
__device__ __forceinline__ void pack_ssp(const float* v, int t, u16* ldsH, u16* ldsL) {
    int r = t >> 3, q = t & 7;
    int s = r & 7;
#pragma unroll
    for (int j = 0; j < 4; ++j) {
        float h0 = sspf(v[4 * j]), h1 = sspf(v[4 * j + 1]);
        float h2 = sspf(v[4 * j + 2]), h3 = sspf(v[4 * j + 3]);
        u32 a, b, c, d;
        split_pair(h0, h1, a, b);
        split_pair(h2, h3, c, d);
        int gc = q * 2 + (j >> 1);
        int off = r * 128 + ((gc ^ s) << 3) + (j & 1) * 4;
        *(uint2*)(ldsH + off) = make_uint2(a, c);
        *(uint2*)(ldsL + off) = make_uint2(b, d);
    }
}
__device__ __forceinline__ void zero_rows(float* A, int M, int m0, int t) {
    int r = t >> 3, q = t & 7;
    int row = m0 + r;
    if (row < M) {
        float4* dst = (float4*)(A + (size_t)row * HD + q * 16);
        float4 z = make_float4(0.f, 0.f, 0.f, 0.f);
#pragma unroll
        for (int j = 0; j < 4; ++j) dst[j] = z;
    }
}
__device__ __forceinline__ void stage_split(const float* __restrict__ A, int M,
                                            int m0, int t, u16* ldsH, u16* ldsL) {
    float v[16];
    gather_rows(A, M, m0, t, v);
    pack_raw(v, t, ldsH, ldsL);
}

// write ssp(acc+bias) back to planes (own col-slice, all rows)
__device__ __forceinline__ void h_store(u16* ldsH, u16* ldsL, int wid, int lane,
                                        const f32x4 acc[4], const float* __restrict__ bias) {
    int l15 = lane & 15, lq = lane >> 4;
    int col = wid * 16 + l15;
    float bb = bias[col];
    int gc = col >> 3, wg = col & 7;
#pragma unroll
    for (int m = 0; m < 4; ++m) {
#pragma unroll
        for (int r = 0; r < 4; ++r) {
            int row = m * 16 + lq * 4 + r;
            float h = sspf(acc[m][r] + bb);
            u32 u = f2u(h);
            u32 hh = (u + 0x7fffu + ((u >> 16) & 1u)) & 0xffff0000u;
            float lf = h - u2f(hh);
            int off = row * 128 + ((gc ^ (row & 7)) << 3) + wg;
            ldsH[off] = (u16)(hh >> 16);
            ldsL[off] = (u16)(f2u(lf) >> 16);
        }
    }
}
__device__ __forceinline__ void v_store(u16* ldsH, u16* ldsL, int wid, int lane,
                                        int m, int r, float val) {
    int l15 = lane & 15, lq = lane >> 4;
    int col = wid * 16 + l15;
    int gc = col >> 3, wg = col & 7;
    int row = m * 16 + lq * 4 + r;
    u32 u = f2u(val);
    u32 hh = (u + 0x7fffu + ((u >> 16) & 1u)) & 0xffff0000u;
    float lf = val - u2f(hh);
    int off = row * 128 + ((gc ^ (row & 7)) << 3) + wg;
    ldsH[off] = (u16)(hh >> 16);
    ldsL[off] = (u16)(f2u(lf) >> 16);
}

// ---------- weight conversion ----------
__global__ void convert_w_k(const float* __restrict__ Wn1, const float* __restrict__ Wn2,
                            const float* __restrict__ gW1, const float* __restrict__ gW2,
                            const float* __restrict__ tW1, const float* __restrict__ tW2,
                            const float* __restrict__ rW1, u16* __restrict__ Wb) {
    int m = blockIdx.x;
    const float* src;
    if (m < 6)       src = Wn1 + (size_t)(m >> 1) * (2 * HD * HD) + (size_t)(m & 1) * (HD * HD);
    else if (m < 9)  src = Wn2 + (size_t)(m - 6) * HD * HD;
    else if (m < 12) src = gW1 + (size_t)(m - 9) * HD * HD;
    else if (m < 15) src = gW2 + (size_t)(m - 12) * HD * HD;
    else if (m < 18) src = tW1 + (size_t)(m - 15) * HD * HD;
    else if (m < 21) src = tW2 + (size_t)(m - 18) * HD * HD;
    else             src = rW1;
    int t = threadIdx.x;
    int lane = t & 63, nn = t >> 6;
    u16* dh = Wb + (size_t)m * (2 * PLANE);
    u16* dl = dh + PLANE;
    for (int c = 0; c < 4; ++c) {
        for (int hh = 0; hh < 2; ++hh) {
            int n = nn + hh * 4;
            int col = n * 16 + (lane & 15);
            int k0 = c * 32 + (lane >> 4) * 8;
            u32 hv[4], lv[4];
#pragma unroll
            for (int jj = 0; jj < 4; ++jj) {
                float wA = src[(size_t)(k0 + 2 * jj) * HD + col];
                float wB = src[(size_t)(k0 + 2 * jj + 1) * HD + col];
                u16 ha = bf16rn(wA), hb = bf16rn(wB);
                u16 la = bf16rn(wA - u2f((u32)ha << 16));
                u16 lb = bf16rn(wB - u2f((u32)hb << 16));
                hv[jj] = (u32)ha | ((u32)hb << 16);
                lv[jj] = (u32)la | ((u32)lb << 16);
            }
            size_t off = ((size_t)(c * 8 + n) * 64 + lane) * 8;
            *(uint4*)(dh + off) = make_uint4(hv[0], hv[1], hv[2], hv[3]);
            *(uint4*)(dl + off) = make_uint4(lv[0], lv[1], lv[2], lv[3]);
        }
    }
}

// ---------- gates lookup table ----------
__global__ void gate_table_k(const float* __restrict__ We1, const float* __restrict__ be1,
                             const float* __restrict__ We2, const float* __restrict__ be2,
                             float* __restrict__ gtab) {
    int row = blockIdx.x;
    int l = row / (NBIN + 1);
    int i = row % (NBIN + 1);
    int j = threadIdx.x;
    float d = (CUTOFFF / NBIN) * (float)i;
    __shared__ float h1[HD];
    const float* w1 = We1 + (size_t)l * 16 * HD;
    float acc = be1[l * HD + j];
#pragma unroll
    for (int k = 0; k < 16; ++k) {
        float dd = d - 0.25f * (float)k;
        float es = __builtin_amdgcn_exp2f(-dd * dd * 8.0f * 1.44269504088896341f);
        acc = fmaf(es, w1[k * HD + j], acc);
    }
    h1[j] = sspf(acc);
    __syncthreads();
    const float* w2 = We2 + (size_t)l * HD * HD;
    float acc2 = be2[l * HD + j];
    for (int k = 0; k < HD; ++k) acc2 = fmaf(h1[k], w2[k * HD + j], acc2);
    float sc = 1.f - sigf(5.f * (d - (CUTOFFF - 1.5f)));
    gtab[(size_t)row * HD + j] = acc2 * sc;
}

// ---------- layer-0 constant gate ----------
__global__ void gate0_k(const float* __restrict__ gW2, const float* __restrict__ gb1,
                        const float* __restrict__ gb2, float* __restrict__ g0v) {
    int j = threadIdx.x;
    __shared__ float h[HD];
    h[j] = sspf(gb1[j]);
    __syncthreads();
    float acc = gb2[j];
    for (int k = 0; k < HD; ++k) acc = fmaf(h[k], gW2[k * HD + j], acc);
    g0v[j] = sigf(acc);
}

// ---------- CSR sort ----------
__global__ __launch_bounds__(256) void hist_k(const int* __restrict__ pe, u32* __restrict__ cnt) {
    int e = blockIdx.x * 256 + threadIdx.x;
    if (e < NEDGE) atomic_add_u(&cnt[pe[2 * e + 1]], 1u);
}

__global__ __launch_bounds__(256) void bsum_k(const u32* __restrict__ cnt, u32* __restrict__ bsum) {
    int i = blockIdx.x * 256 + threadIdx.x;
    int v = (i < NPROBE) ? (int)cnt[i] : 0;
#pragma unroll
    for (int d = 1; d < 64; d <<= 1) v += __shfl_xor(v, d);
    __shared__ int wsum[4];
    if ((threadIdx.x & 63) == 0) wsum[threadIdx.x >> 6] = v;
    __syncthreads();
    if (threadIdx.x == 0) bsum[blockIdx.x] = (u32)(wsum[0] + wsum[1] + wsum[2] + wsum[3]);
}

__global__ __launch_bounds__(512) void bscan_k(u32* __restrict__ bsum) {
    __shared__ u32 s[512];
    int t = threadIdx.x;
    u32 v = (t < NSBLK) ? bsum[t] : 0u;
    s[t] = v;
    __syncthreads();
    for (int d = 1; d < 512; d <<= 1) {
        u32 x = (t >= d) ? s[t - d] : 0u;
        __syncthreads();
        s[t] += x;
        __syncthreads();
    }
    if (t < NSBLK) bsum[t] = s[t] - v;
}

__global__ __launch_bounds__(256) void cur_k(const u32* __restrict__ cnt,
                                             const u32* __restrict__ bsum, u32* __restrict__ cur) {
    __shared__ u32 s[256];
    int b = blockIdx.x, t = threadIdx.x;
    int i = b * 256 + t;
    u32 v = (i < NPROBE) ? cnt[i] : 0u;
    s[t] = v;
    __syncthreads();
    for (int d = 1; d < 256; d <<= 1) {
        u32 x = (t >= d) ? s[t - d] : 0u;
        __syncthreads();
        s[t] += x;
        __syncthreads();
    }
    if (i < NPROBE) cur[i] = bsum[b] + s[t] - v;
}

__global__ __launch_bounds__(256) void scatter_k(const int* __restrict__ pe,
                                                 u32* __restrict__ cur, u32* __restrict__ eord) {
    int e = blockIdx.x * 256 + threadIdx.x;
    if (e < NEDGE) {
        u32 pos = atomic_add_u(&cur[pe[2 * e + 1]], 1u);
        eord[pos] = (u32)e;
    }
}

// ---------- atom projection ----------
#define ABLK 313
__global__ __launch_bounds__(NT, 4) void gemm_atoms_k(const float* __restrict__ atom_rep,
                                                      const u16* __restrict__ Wb,
                                                      const float* __restrict__ bn1,
                                                      float* __restrict__ Xab) {
    __shared__ u16 ldsH[MT * 128];
    __shared__ u16 ldsL[MT * 128];
    int l = blockIdx.x / ABLK;
    int mb = blockIdx.x % ABLK;
    const float* A = atom_rep + (size_t)l * NATOM * HD;
    const u16* W = Wb + (size_t)(2 * l) * 2 * PLANE;
    float* outp = Xab + (size_t)l * NATOM * HD;
    int m0 = mb * MT, t = threadIdx.x;
    stage_split(A, NATOM, m0, t, ldsH, ldsL);
    bar_lds();
    int lane = t & 63, wid = t >> 6;
    int l15 = lane & 15, lq = lane >> 4;
    int col = wid * 16 + l15;
    f32x4 acc[4] = {};
    mma_slice(ldsH, ldsL, lane, wid, W, acc);
    float bv = bn1[l * HD + col];
#pragma unroll
    for (int m = 0; m < 4; ++m) {
#pragma unroll
        for (int r = 0; r < 4; ++r) {
            int row = m0 + m * 16 + lq * 4 + r;
            if (row < NATOM) outp[(size_t)row * HD + col] = acc[m][r] + bv;
        }
    }
}

// ---------- edge kernel helpers ----------
__device__ __forceinline__ void gather_edge(
        int e0, int t, const float* __restrict__ Xab, const float* __restrict__ Xp,
        const int* __restrict__ pe, const u32* __restrict__ eord,
        const float* __restrict__ dist,
        int* rcv_s, float* fr_s, int* ib_s, float* sum) {
    int r = t >> 3, q = t & 7;
    int e = (int)eord[e0 + r];
    int snd = pe[2 * e], rcv = pe[2 * e + 1];
    if (q == 0) {
        rcv_s[r] = rcv;
        float x = dist[e] * ((float)NBIN / CUTOFFF);
        int i = (int)x;
        i = i < (NBIN - 1) ? i : (NBIN - 1);
        fr_s[r] = x - (float)i;
        ib_s[r] = i;
    }
    const float4* xa = (const float4*)(Xab + (size_t)snd * HD + q * 16);
    const float4* xp = Xp ? (const float4*)(Xp + (size_t)rcv * HD + q * 16) : nullptr;
#pragma unroll
    for (int j = 0; j < 4; ++j) {
        float4 va = xa[j];
        if (xp) {
            float4 vp = xp[j];
            va.x += vp.x; va.y += vp.y; va.z += vp.z; va.w += vp.w;
        }
        sum[4 * j] = va.x; sum[4 * j + 1] = va.y;
        sum[4 * j + 2] = va.z; sum[4 * j + 3] = va.w;
    }
}

__device__ __forceinline__ void edge_out(const f32x4 acc[4], const int* rcv_s,
        const float* fr_s, const int* ib_s, const float* __restrict__ gtab,
        float bb, int col, int lq, float* __restrict__ msgsum) {
#pragma unroll
    for (int m = 0; m < 4; ++m) {
        int rbase = m * 16 + lq * 4;
        float vals[4];
        int rc[4];
#pragma unroll
        for (int r = 0; r < 4; ++r) {
            int er = rbase + r;
            rc[r] = rcv_s[er];
            const float* gp = gtab + (size_t)ib_s[er] * HD;
            float ga = gp[col], gb = gp[HD + col];
            vals[r] = (acc[m][r] + bb) * fmaf(gb - ga, fr_s[er], ga);
        }
#pragma unroll
        for (int r = 3; r >= 1; --r) {
            if (rc[r] == rc[r - 1]) {
                vals[r - 1] += vals[r];
            } else {
                atomic_add_f(msgsum + (size_t)rc[r] * HD + col, vals[r]);
            }
        }
        atomic_add_f(msgsum + (size_t)rc[0] * HD + col, vals[0]);
    }
}

// ---------- edge kernel: 2-tile pipelined ----------
__global__ __launch_bounds__(NT, 4) void edge_msg_k(
        const float* __restrict__ Xab, const float* __restrict__ Xp,
        const u16* __restrict__ W2b, const float* __restrict__ bn2,
        const float* __restrict__ gtab, const float* __restrict__ dist,
        const int* __restrict__ pe, const u32* __restrict__ eord,
        float* __restrict__ msgsum) {
    __shared__ u16 ldsH[2][MT * 128];
    __shared__ u16 ldsL[2][MT * 128];
    __shared__ int rcv_s[2][MT];
    __shared__ float fr_s[2][MT];
    __shared__ int ib_s[2][MT];
    int t = threadIdx.x;
    int lane = t & 63, wid = t >> 6;
    int l15 = lane & 15, lq = lane >> 4;
    int col = wid * 16 + l15;
    int e0 = blockIdx.x * (2 * MT);

    bf16x8 Bh[4], Bl[4];
    load_bfrags(W2b, lane, wid, Bh, Bl);   // invariant across both tiles
    float bb = bn2[col];

    float s0[16], s1[16];
    gather_edge(e0, t, Xab, Xp, pe, eord, dist, rcv_s[0], fr_s[0], ib_s[0], s0);
    gather_edge(e0 + MT, t, Xab, Xp, pe, eord, dist, rcv_s[1], fr_s[1], ib_s[1], s1);
    pack_ssp(s0, t, ldsH[0], ldsL[0]);
    bar_lds();

    f32x4 acc0[4] = {};
    mma_slice_pre(ldsH[0], ldsL[0], lane, Bh, Bl, acc0);
    pack_ssp(s1, t, ldsH[1], ldsL[1]);
    edge_out(acc0, rcv_s[0], fr_s[0], ib_s[0], gtab, bb, col, lq, msgsum);
    bar_lds();   // atomics stay in flight (lgkm-only)

    f32x4 acc1[4] = {};
    mma_slice_pre(ldsH[1], ldsL[1], lane, Bh, Bl, acc1);
    edge_out(acc1, rcv_s[1], fr_s[1], ib_s[1], gtab, bb, col, lq, msgsum);
}

// ---------- fused probe update (interleaved gate/trans, double-buffered) ----------
// g0v != nullptr => layer 0 (gate = const, ps = 0). msgzero: zero msgsum rows for next layer.
__global__ __launch_bounds__(NT, 4) void probe_update_k(
        const float* ps, const float* msgsum, float* msgzero,
        const u16* __restrict__ gW1b, const float* __restrict__ gb1,
        const u16* __restrict__ gW2b, const float* __restrict__ gb2,
        const u16* __restrict__ tW1b, const float* __restrict__ tb1,
        const u16* __restrict__ tW2b, const float* __restrict__ tb2,
        const u16* __restrict__ W3b,
        const u16* __restrict__ rW1b, const float* __restrict__ rb1,
        const float* __restrict__ rW2, const float* __restrict__ rb2,
        const float* __restrict__ g0v,
        float* psout, float* __restrict__ xpout, float* __restrict__ outp) {
    __shared__ u16 ldsH[2][MT * 128];
    __shared__ u16 ldsL[2][MT * 128];
    __shared__ float parts[MT][9];
    int m0 = blockIdx.x * MT, t = threadIdx.x;
    int lane = t & 63, wid = t >> 6;
    int l15 = lane & 15, lq = lane >> 4;
    int col = wid * 16 + l15;

    f32x4 g[4] = {};
    f32x4 tv[4] = {};
    int vbuf;   // buffer that receives combined vals for projection

    if (!g0v) {
        // buf0 = ps (gate path), buf1 = msgsum (trans path), interleaved
        float sp[16], sm[16];
        gather_rows(ps, NPROBE, m0, t, sp);
        gather_rows(msgsum, NPROBE, m0, t, sm);
        pack_raw(sp, t, ldsH[0], ldsL[0]);
        bar_lds();
        pack_raw(sm, t, ldsH[1], ldsL[1]);
        if (msgzero) zero_rows(msgzero, NPROBE, m0, t);   // loads consumed by pack's ds_writes
        mma_slice(ldsH[0], ldsL[0], lane, wid, gW1b, g);
        bar_lds();
        h_store(ldsH[0], ldsL[0], wid, lane, g, gb1);
        mma_slice(ldsH[1], ldsL[1], lane, wid, tW1b, tv);
        bar_lds();
#pragma unroll
        for (int m = 0; m < 4; ++m) g[m] = (f32x4){0.f, 0.f, 0.f, 0.f};
        mma_slice(ldsH[0], ldsL[0], lane, wid, gW2b, g);
        float gb2v = gb2[col];
#pragma unroll
        for (int m = 0; m < 4; ++m)
#pragma unroll
            for (int r = 0; r < 4; ++r) g[m][r] = sigf(g[m][r] + gb2v);
        h_store(ldsH[1], ldsL[1], wid, lane, tv, tb1);
        bar_lds();
#pragma unroll
        for (int m = 0; m < 4; ++m) tv[m] = (f32x4){0.f, 0.f, 0.f, 0.f};
        mma_slice(ldsH[1], ldsL[1], lane, wid, tW2b, tv);
        vbuf = 0;   // buf0 reads done at previous barrier
    } else {
        // layer 0: only trans path; const gate
        float sm[16];
        gather_rows(msgsum, NPROBE, m0, t, sm);
        pack_raw(sm, t, ldsH[0], ldsL[0]);
        if (msgzero) zero_rows(msgzero, NPROBE, m0, t);
        bar_lds();
        mma_slice(ldsH[0], ldsL[0], lane, wid, tW1b, tv);
        bar_lds();
        h_store(ldsH[0], ldsL[0], wid, lane, tv, tb1);
        bar_lds();
#pragma unroll
        for (int m = 0; m < 4; ++m) tv[m] = (f32x4){0.f, 0.f, 0.f, 0.f};
        mma_slice(ldsH[0], ldsL[0], lane, wid, tW2b, tv);
        float gv = g0v[col];
#pragma unroll
        for (int m = 0; m < 4; ++m)
#pragma unroll
            for (int r = 0; r < 4; ++r) g[m][r] = gv;
        vbuf = 1;   // buf1 untouched in this path
    }

    // ---- combine: ps_new = ps*g + (1-g)*t ; stash vals into vbuf planes ----
    float tb2v = tb2[col];
#pragma unroll
    for (int m = 0; m < 4; ++m) {
#pragma unroll
        for (int r = 0; r < 4; ++r) {
            int row = m0 + m * 16 + lq * 4 + r;
            float val = 0.f;
            if (row < NPROBE) {
                size_t idx = (size_t)row * HD + col;
                float tval = tv[m][r] + tb2v;
                float pv = g0v ? 0.f : ps[idx];
                val = fmaf(pv - tval, g[m][r], tval);
                if (!rW1b) psout[idx] = val;
            }
            v_store(ldsH[vbuf], ldsL[vbuf], wid, lane, m, r, val);
        }
    }
    bar_lds();

    if (W3b) {
        f32x4 a[4] = {};
        mma_slice(ldsH[vbuf], ldsL[vbuf], lane, wid, W3b, a);
#pragma unroll
        for (int m = 0; m < 4; ++m)
#pragma unroll
            for (int r = 0; r < 4; ++r) {
                int row = m0 + m * 16 + lq * 4 + r;
                if (row < NPROBE) xpout[(size_t)row * HD + col] = a[m][r];
            }
    } else if (rW1b) {
        f32x4 a[4] = {};
        mma_slice(ldsH[vbuf], ldsL[vbuf], lane, wid, rW1b, a);
        float rb1v = rb1[col], w2v = rW2[col];
#pragma unroll
        for (int m = 0; m < 4; ++m)
#pragma unroll
            for (int r = 0; r < 4; ++r) {
                float p = sspf(a[m][r] + rb1v) * w2v;
                p += __shfl_xor(p, 1, 16);
                p += __shfl_xor(p, 2, 16);
                p += __shfl_xor(p, 4, 16);
                p += __shfl_xor(p, 8, 16);
                if (l15 == 0) parts[m * 16 + lq * 4 + r][wid] = p;
            }
        bar_lds();
        if (t < MT) {
            int row = m0 + t;
            if (row < NPROBE) {
                float s = rb2[0];
#pragma unroll
                for (int w = 0; w < 8; ++w) s += parts[t][w];
                outp[row] = s;
            }
        }
    }
}

// ---------- launcher ----------
extern "C" void kernel_launch(void* const* d_in, const int* in_sizes, int n_in,
                              void* d_out, int out_size, void* d_ws, size_t ws_size,
                              hipStream_t stream) {
    const float* atom_rep = (const float*)d_in[0];
    const float* dist     = (const float*)d_in[1];
    const float* We1 = (const float*)d_in[2];
    const float* be1 = (const float*)d_in[3];
    const float* We2 = (const float*)d_in[4];
    const float* be2 = (const float*)d_in[5];
    const float* Wn1 = (const float*)d_in[6];
    const float* bn1 = (const float*)d_in[7];
    const float* Wn2 = (const float*)d_in[8];
    const float* bn2 = (const float*)d_in[9];
    const float* gW1 = (const float*)d_in[10];
    const float* gb1 = (const float*)d_in[11];
    const float* gW2 = (const float*)d_in[12];
    const float* gb2 = (const float*)d_in[13];
    const float* tW1 = (const float*)d_in[14];
    const float* tb1 = (const float*)d_in[15];
    const float* tW2 = (const float*)d_in[16];
    const float* tb2 = (const float*)d_in[17];
    const float* rW1 = (const float*)d_in[18];
    const float* rb1 = (const float*)d_in[19];
    const float* rW2 = (const float*)d_in[20];
    const float* rb2 = (const float*)d_in[21];
    const int*   pe  = (const int*)d_in[22];
    float* out = (float*)d_out;

    float* ws = (float*)d_ws;
    float* ps     = ws;                         // 12,800,000 f
    float* msgsum = ps + 12800000u;             // 12,800,000 f
    float* Xp     = msgsum + 12800000u;         // 12,800,000 f
    float* Xab    = Xp + 12800000u;             // 3 * 2,560,000 f
    float* gtab   = Xab + 7680000u;             // 786,816 f
    float* g0v    = gtab + 786816u;             // 128 f
    u16*   Wb     = (u16*)(g0v + 128);          // 22*2*PLANE u16
    u32*   cnt    = (u32*)(Wb + 22 * 2 * PLANE);
    u32*   bsum   = cnt + NPROBE;               // NSBLK
    u32*   cur    = bsum + 512;
    u32*   eord   = cur + NPROBE;

    const int PBLK = (NPROBE + MT - 1) / MT;   // 1563
    const int EBLK = NEDGE / (2 * MT);         // 3125
    const int TBLK = (NEDGE + 255) / 256;      // 1563

    hipMemsetAsync(cnt, 0, (size_t)NPROBE * 4, stream);
    hipMemsetAsync(msgsum, 0, 12800000ull * 4, stream);
    convert_w_k<<<22, 256, 0, stream>>>(Wn1, Wn2, gW1, gW2, tW1, tW2, rW1, Wb);
    gate_table_k<<<NLAYER * (NBIN + 1), HD, 0, stream>>>(We1, be1, We2, be2, gtab);
    gate0_k<<<1, HD, 0, stream>>>(gW2, gb1, gb2, g0v);
    hist_k<<<TBLK, 256, 0, stream>>>(pe, cnt);
    bsum_k<<<NSBLK, 256, 0, stream>>>(cnt, bsum);
    bscan_k<<<1, 512, 0, stream>>>(bsum);
    cur_k<<<NSBLK, 256, 0, stream>>>(cnt, bsum, cur);
    scatter_k<<<TBLK, 256, 0, stream>>>(pe, cur, eord);
    gemm_atoms_k<<<NLAYER * ABLK, NT, 0, stream>>>(atom_rep, Wb, bn1, Xab);

    for (int l = 0; l < NLAYER; ++l) {
        edge_msg_k<<<EBLK, NT, 0, stream>>>(Xab + (size_t)l * NATOM * HD,
                                            (l == 0) ? nullptr : Xp,
                                            Wb + (size_t)(6 + l) * 2 * PLANE,
                                            bn2 + l * HD,
                                            gtab + (size_t)l * (NBIN + 1) * HD,
                                            dist, pe, eord, msgsum);
        const u16* W3  = (l < NLAYER - 1) ? Wb + (size_t)(2 * (l + 1) + 1) * 2 * PLANE : nullptr;
        const u16* RW1 = (l == NLAYER - 1) ? Wb + (size_t)21 * 2 * PLANE : nullptr;
        float* mz = (l < NLAYER - 1) ? msgsum : nullptr;
        probe_update_k<<<PBLK, NT, 0, stream>>>(ps, msgsum, mz,
                                                Wb + (size_t)(9 + l) * 2 * PLANE, gb1 + l * HD,
                                                Wb + (size_t)(12 + l) * 2 * PLANE, gb2 + l * HD,
                                                Wb + (size_t)(15 + l) * 2 * PLANE, tb1 + l * HD,
                                                Wb + (size_t)(18 + l) * 2 * PLANE, tb2 + l * HD,
                                                W3, RW1, rb1, rW2, rb2,
                                                (l == 0) ? g0v : nullptr,
                                                ps, Xp, out);
    }
}

// Round 8
// 706.751 us; speedup vs baseline: 2.0949x; 1.1022x over previous
//
#include <hip/hip_runtime.h>

#define NLAYER 3
#define NATOM 20000
#define NPROBE 100000
#define NEDGE 400000
#define HD 128
#define NBIN 2048
#define CUTOFFF 4.0f
#define PLANE 16384   // ushorts per bf16 plane (128x128)
#define MT 64         // row tile
#define NT 512        // threads per block (8 waves)
#define NSBLK ((NPROBE + 255) / 256)   // 391 scan blocks

typedef unsigned int u32;
typedef unsigned short u16;
typedef __attribute__((ext_vector_type(8))) short bf16x8;
typedef __attribute__((ext_vector_type(4))) float f32x4;

// ---------- math helpers ----------
__device__ __forceinline__ float sspf(float x) {
    float e = __builtin_amdgcn_exp2f(fminf(x, 80.f) * 1.44269504088896341f);
    return 0.69314718055994531f * (__builtin_amdgcn_logf(1.f + e) - 1.f);
}
__device__ __forceinline__ float sigf(float x) {
    return 1.f / (1.f + __builtin_amdgcn_exp2f(-x * 1.44269504088896341f));
}
__device__ __forceinline__ void atomic_add_f(float* p, float v) {
    __hip_atomic_fetch_add(p, v, __ATOMIC_RELAXED, __HIP_MEMORY_SCOPE_AGENT);
}
__device__ __forceinline__ u32 atomic_add_u(u32* p, u32 v) {
    return __hip_atomic_fetch_add(p, v, __ATOMIC_RELAXED, __HIP_MEMORY_SCOPE_AGENT);
}
__device__ __forceinline__ u32 f2u(float f) { union { float f; u32 u; } x; x.f = f; return x.u; }
__device__ __forceinline__ float u2f(u32 u) { union { float f; u32 u; } x; x.u = u; return x.f; }
__device__ __forceinline__ u16 bf16rn(float f) {
    u32 u = f2u(f);
    u32 r = u + 0x7fffu + ((u >> 16) & 1u);
    return (u16)(r >> 16);
}
__device__ __forceinline__ void split_pair(float x, float y, u32& hi, u32& lo) {
    u32 ux = f2u(x);
    u32 hx = (ux + 0x7fffu + ((ux >> 16) & 1u)) & 0xffff0000u;
    float lxf = x - u2f(hx);
    u32 uy = f2u(y);
    u32 hy = (uy + 0x7fffu + ((uy >> 16) & 1u)) & 0xffff0000u;
    float lyf = y - u2f(hy);
    hi = (hx >> 16) | hy;
    lo = (f2u(lxf) >> 16) | (f2u(lyf) & 0xffff0000u);
}

// LDS-only barrier: do NOT drain vmcnt (atomics / prefetch loads stay in flight).
__device__ __forceinline__ void bar_lds() {
    asm volatile("s_waitcnt lgkmcnt(0)" ::: "memory");
    __builtin_amdgcn_s_barrier();
}

// ---------- MFMA core: weight-stationary column slice ----------
__device__ __forceinline__ void load_bfrags(const u16* __restrict__ Wb, int lane, int wid,
                                            bf16x8 Bh[4], bf16x8 Bl[4]) {
    const bf16x8* Bhp = (const bf16x8*)Wb;
    const bf16x8* Blp = (const bf16x8*)(Wb + PLANE);
#pragma unroll
    for (int c = 0; c < 4; ++c) {
        Bh[c] = Bhp[(size_t)(c * 8 + wid) * 64 + lane];
        Bl[c] = Blp[(size_t)(c * 8 + wid) * 64 + lane];
    }
}

__device__ __forceinline__ void mma_slice_pre(const u16* __restrict__ ldsH,
                                              const u16* __restrict__ ldsL,
                                              int lane, const bf16x8 Bh[4], const bf16x8 Bl[4],
                                              f32x4 acc[4]) {
    int l15 = lane & 15, kq = lane >> 4;
#pragma unroll
    for (int m = 0; m < 4; ++m) {
        int row = m * 16 + l15;
        int s = row & 7;
        const u16* hp = ldsH + row * 128;
        const u16* lp = ldsL + row * 128;
#pragma unroll
        for (int c = 0; c < 4; ++c) {
            int off = ((c * 4 + kq) ^ s) << 3;
            bf16x8 Ah = *(const bf16x8*)(hp + off);
            bf16x8 Al = *(const bf16x8*)(lp + off);
            acc[m] = __builtin_amdgcn_mfma_f32_16x16x32_bf16(Ah, Bh[c], acc[m], 0, 0, 0);
            acc[m] = __builtin_amdgcn_mfma_f32_16x16x32_bf16(Al, Bh[c], acc[m], 0, 0, 0);
            acc[m] = __builtin_amdgcn_mfma_f32_16x16x32_bf16(Ah, Bl[c], acc[m], 0, 0, 0);
        }
    }
}

__device__ __forceinline__ void mma_slice(const u16* __restrict__ ldsH,
                                          const u16* __restrict__ ldsL,
                                          int lane, int wid,
                                          const u16* __restrict__ Wb,
                                          f32x4 acc[4]) {
    bf16x8 Bh[4], Bl[4];
    load_bfrags(Wb, lane, wid, Bh, Bl);
    mma_slice_pre(ldsH, ldsL, lane, Bh, Bl, acc);
}

// ---------- staging helpers ----------
// pack 16 fp32 (cols q*16..+15 of `row`) into split planes, full 16B writes.
__device__ __forceinline__ void pack_store(const float* v, int row, int q,
                                           u16* ldsH, u16* ldsL) {
    int s = row & 7;
#pragma unroll
    for (int h = 0; h < 2; ++h) {
        u32 hv[4], lv[4];
#pragma unroll
        for (int k = 0; k < 4; ++k)
            split_pair(v[8 * h + 2 * k], v[8 * h + 2 * k + 1], hv[k], lv[k]);
        int gc = q * 2 + h;
        int off = row * 128 + ((gc ^ s) << 3);
        *(uint4*)(ldsH + off) = make_uint4(hv[0], hv[1], hv[2], hv[3]);
        *(uint4*)(ldsL + off) = make_uint4(lv[0], lv[1], lv[2], lv[3]);
    }
}

__device__ __forceinline__ void gather_rows(const float* __restrict__ A, int M,
                                            int m0, int t, float* v) {
    int r = t >> 3, q = t & 7;
    int row = m0 + r;
    bool ok = row < M;
    const float4* src = (const float4*)(A + (size_t)row * HD + q * 16);
#pragma unroll
    for (int j = 0; j < 4; ++j) {
        float4 x = ok ? src[j] : make_float4(0.f, 0.f, 0.f, 0.f);
        v[4 * j] = x.x; v[4 * j + 1] = x.y; v[4 * j + 2] = x.z; v[4 * j + 3] = x.w;
    }
}
__device__ __forceinline__ void zero_rows(float* A, int M, int m0, int t) {
    int r = t >> 3, q = t & 7;
    int row = m0 + r;
    if (row < M) {
        float4* dst = (float4*)(A + (size_t)row * HD + q * 16);
        float4 z = make_float4(0.f, 0.f, 0.f, 0.f);
#pragma unroll
        for (int j = 0; j < 4; ++j) dst[j] = z;
    }
}
__device__ __forceinline__ void stage_split(const float* __restrict__ A, int M,
                                            int m0, int t, u16* ldsH, u16* ldsL) {
    float v[16];
    gather_rows(A, M, m0, t, v);
    pack_store(v, t >> 3, t & 7, ldsH, ldsL);
}

// write ssp(acc+bias) back to planes (own col-slice, all rows)
__device__ __forceinline__ void h_store(u16* ldsH, u16* ldsL, int wid, int lane,
                                        const f32x4 acc[4], const float* __restrict__ bias) {
    int l15 = lane & 15, lq = lane >> 4;
    int col = wid * 16 + l15;
    float bb = bias[col];
    int gc = col >> 3, wg = col & 7;
#pragma unroll
    for (int m = 0; m < 4; ++m) {
#pragma unroll
        for (int r = 0; r < 4; ++r) {
            int row = m * 16 + lq * 4 + r;
            float h = sspf(acc[m][r] + bb);
            u32 u = f2u(h);
            u32 hh = (u + 0x7fffu + ((u >> 16) & 1u)) & 0xffff0000u;
            float lf = h - u2f(hh);
            int off = row * 128 + ((gc ^ (row & 7)) << 3) + wg;
            ldsH[off] = (u16)(hh >> 16);
            ldsL[off] = (u16)(f2u(lf) >> 16);
        }
    }
}
__device__ __forceinline__ void v_store(u16* ldsH, u16* ldsL, int wid, int lane,
                                        int m, int r, float val) {
    int l15 = lane & 15, lq = lane >> 4;
    int col = wid * 16 + l15;
    int gc = col >> 3, wg = col & 7;
    int row = m * 16 + lq * 4 + r;
    u32 u = f2u(val);
    u32 hh = (u + 0x7fffu + ((u >> 16) & 1u)) & 0xffff0000u;
    float lf = val - u2f(hh);
    int off = row * 128 + ((gc ^ (row & 7)) << 3) + wg;
    ldsH[off] = (u16)(hh >> 16);
    ldsL[off] = (u16)(f2u(lf) >> 16);
}

// ---------- weight conversion ----------
__global__ void convert_w_k(const float* __restrict__ Wn1, const float* __restrict__ Wn2,
                            const float* __restrict__ gW1, const float* __restrict__ gW2,
                            const float* __restrict__ tW1, const float* __restrict__ tW2,
                            const float* __restrict__ rW1, u16* __restrict__ Wb) {
    int m = blockIdx.x;
    const float* src;
    if (m < 6)       src = Wn1 + (size_t)(m >> 1) * (2 * HD * HD) + (size_t)(m & 1) * (HD * HD);
    else if (m < 9)  src = Wn2 + (size_t)(m - 6) * HD * HD;
    else if (m < 12) src = gW1 + (size_t)(m - 9) * HD * HD;
    else if (m < 15) src = gW2 + (size_t)(m - 12) * HD * HD;
    else if (m < 18) src = tW1 + (size_t)(m - 15) * HD * HD;
    else if (m < 21) src = tW2 + (size_t)(m - 18) * HD * HD;
    else             src = rW1;
    int t = threadIdx.x;
    int lane = t & 63, nn = t >> 6;
    u16* dh = Wb + (size_t)m * (2 * PLANE);
    u16* dl = dh + PLANE;
    for (int c = 0; c < 4; ++c) {
        for (int hh = 0; hh < 2; ++hh) {
            int n = nn + hh * 4;
            int col = n * 16 + (lane & 15);
            int k0 = c * 32 + (lane >> 4) * 8;
            u32 hv[4], lv[4];
#pragma unroll
            for (int jj = 0; jj < 4; ++jj) {
                float wA = src[(size_t)(k0 + 2 * jj) * HD + col];
                float wB = src[(size_t)(k0 + 2 * jj + 1) * HD + col];
                u16 ha = bf16rn(wA), hb = bf16rn(wB);
                u16 la = bf16rn(wA - u2f((u32)ha << 16));
                u16 lb = bf16rn(wB - u2f((u32)hb << 16));
                hv[jj] = (u32)ha | ((u32)hb << 16);
                lv[jj] = (u32)la | ((u32)lb << 16);
            }
            size_t off = ((size_t)(c * 8 + n) * 64 + lane) * 8;
            *(uint4*)(dh + off) = make_uint4(hv[0], hv[1], hv[2], hv[3]);
            *(uint4*)(dl + off) = make_uint4(lv[0], lv[1], lv[2], lv[3]);
        }
    }
}

// ---------- paired gates table: gt2[l][i][col] = (g_i[col], g_{i+1}[col]) ----------
__global__ void gate_table_k(const float* __restrict__ We1, const float* __restrict__ be1,
                             const float* __restrict__ We2, const float* __restrict__ be2,
                             float2* __restrict__ gt2) {
    int row = blockIdx.x;                 // l*(NBIN+1) + i, i in 0..NBIN
    int l = row / (NBIN + 1);
    int i = row % (NBIN + 1);
    int j = threadIdx.x;
    float d = (CUTOFFF / NBIN) * (float)i;
    __shared__ float h1[HD];
    const float* w1 = We1 + (size_t)l * 16 * HD;
    float acc = be1[l * HD + j];
#pragma unroll
    for (int k = 0; k < 16; ++k) {
        float dd = d - 0.25f * (float)k;
        float es = __builtin_amdgcn_exp2f(-dd * dd * 8.0f * 1.44269504088896341f);
        acc = fmaf(es, w1[k * HD + j], acc);
    }
    h1[j] = sspf(acc);
    __syncthreads();
    const float* w2 = We2 + (size_t)l * HD * HD;
    float acc2 = be2[l * HD + j];
    for (int k = 0; k < HD; ++k) acc2 = fmaf(h1[k], w2[k * HD + j], acc2);
    float sc = 1.f - sigf(5.f * (d - (CUTOFFF - 1.5f)));
    float val = acc2 * sc;
    float2* base = gt2 + (size_t)l * NBIN * HD;
    if (i < NBIN) base[(size_t)i * HD + j].x = val;
    if (i > 0)    base[(size_t)(i - 1) * HD + j].y = val;
}

// ---------- layer-0 constant gate ----------
__global__ void gate0_k(const float* __restrict__ gW2, const float* __restrict__ gb1,
                        const float* __restrict__ gb2, float* __restrict__ g0v) {
    int j = threadIdx.x;
    __shared__ float h[HD];
    h[j] = sspf(gb1[j]);
    __syncthreads();
    float acc = gb2[j];
    for (int k = 0; k < HD; ++k) acc = fmaf(h[k], gW2[k * HD + j], acc);
    g0v[j] = sigf(acc);
}

// ---------- CSR sort ----------
__global__ __launch_bounds__(256) void hist_k(const int* __restrict__ pe, u32* __restrict__ cnt) {
    int e = blockIdx.x * 256 + threadIdx.x;
    if (e < NEDGE) atomic_add_u(&cnt[pe[2 * e + 1]], 1u);
}

__global__ __launch_bounds__(256) void bsum_k(const u32* __restrict__ cnt, u32* __restrict__ bsum) {
    int i = blockIdx.x * 256 + threadIdx.x;
    int v = (i < NPROBE) ? (int)cnt[i] : 0;
#pragma unroll
    for (int d = 1; d < 64; d <<= 1) v += __shfl_xor(v, d);
    __shared__ int wsum[4];
    if ((threadIdx.x & 63) == 0) wsum[threadIdx.x >> 6] = v;
    __syncthreads();
    if (threadIdx.x == 0) bsum[blockIdx.x] = (u32)(wsum[0] + wsum[1] + wsum[2] + wsum[3]);
}

__global__ __launch_bounds__(512) void bscan_k(u32* __restrict__ bsum) {
    __shared__ u32 s[512];
    int t = threadIdx.x;
    u32 v = (t < NSBLK) ? bsum[t] : 0u;
    s[t] = v;
    __syncthreads();
    for (int d = 1; d < 512; d <<= 1) {
        u32 x = (t >= d) ? s[t - d] : 0u;
        __syncthreads();
        s[t] += x;
        __syncthreads();
    }
    if (t < NSBLK) bsum[t] = s[t] - v;
}

__global__ __launch_bounds__(256) void cur_k(const u32* __restrict__ cnt,
                                             const u32* __restrict__ bsum, u32* __restrict__ cur) {
    __shared__ u32 s[256];
    int b = blockIdx.x, t = threadIdx.x;
    int i = b * 256 + t;
    u32 v = (i < NPROBE) ? cnt[i] : 0u;
    s[t] = v;
    __syncthreads();
    for (int d = 1; d < 256; d <<= 1) {
        u32 x = (t >= d) ? s[t - d] : 0u;
        __syncthreads();
        s[t] += x;
        __syncthreads();
    }
    if (i < NPROBE) cur[i] = bsum[b] + s[t] - v;
}

__global__ __launch_bounds__(256) void scatter_k(const int* __restrict__ pe,
                                                 u32* __restrict__ cur, u32* __restrict__ eord) {
    int e = blockIdx.x * 256 + threadIdx.x;
    if (e < NEDGE) {
        u32 pos = atomic_add_u(&cur[pe[2 * e + 1]], 1u);
        eord[pos] = (u32)e;
    }
}

// ---------- atom projection ----------
#define ABLK 313
__global__ __launch_bounds__(NT, 4) void gemm_atoms_k(const float* __restrict__ atom_rep,
                                                      const u16* __restrict__ Wb,
                                                      const float* __restrict__ bn1,
                                                      float* __restrict__ Xab) {
    __shared__ u16 ldsH[MT * 128];
    __shared__ u16 ldsL[MT * 128];
    int l = blockIdx.x / ABLK;
    int mb = blockIdx.x % ABLK;
    const float* A = atom_rep + (size_t)l * NATOM * HD;
    const u16* W = Wb + (size_t)(2 * l) * 2 * PLANE;
    float* outp = Xab + (size_t)l * NATOM * HD;
    int m0 = mb * MT, t = threadIdx.x;
    stage_split(A, NATOM, m0, t, ldsH, ldsL);
    bar_lds();
    int lane = t & 63, wid = t >> 6;
    int l15 = lane & 15, lq = lane >> 4;
    int col = wid * 16 + l15;
    f32x4 acc[4] = {};
    mma_slice(ldsH, ldsL, lane, wid, W, acc);
    float bv = bn1[l * HD + col];
#pragma unroll
    for (int m = 0; m < 4; ++m) {
#pragma unroll
        for (int r = 0; r < 4; ++r) {
            int row = m0 + m * 16 + lq * 4 + r;
            if (row < NATOM) outp[(size_t)row * HD + col] = acc[m][r] + bv;
        }
    }
}

// ---------- edge kernel helpers ----------
// edge-linear index r -> LDS row such that MFMA acc rows of a thread are
// 16 CONSECUTIVE edges: r = lq*16 + m*4 + reg  <->  row = m*16 + lq*4 + reg.
__device__ __forceinline__ int rho(int r) {
    return ((r >> 2) & 3) * 16 + ((r >> 4) << 2) + (r & 3);
}

// meta: fr_s[r] = lerp frac; mix_s[r] = (rcv << 11) | bin
__device__ __forceinline__ void gather_edge(
        int e0, int t, const float* __restrict__ Xab, const float* __restrict__ Xp,
        const int* __restrict__ pe, const u32* __restrict__ eord,
        const float* __restrict__ dist,
        u32* mix_s, float* fr_s, float* sum) {
    int r = t >> 3, q = t & 7;
    int e = (int)eord[e0 + r];
    int snd = pe[2 * e], rcv = pe[2 * e + 1];
    if (q == 0) {
        float x = dist[e] * ((float)NBIN / CUTOFFF);
        int i = (int)x;
        i = i < (NBIN - 1) ? i : (NBIN - 1);
        fr_s[r] = x - (float)i;
        mix_s[r] = ((u32)rcv << 11) | (u32)i;
    }
    const float4* xa = (const float4*)(Xab + (size_t)snd * HD + q * 16);
    const float4* xp = Xp ? (const float4*)(Xp + (size_t)rcv * HD + q * 16) : nullptr;
#pragma unroll
    for (int j = 0; j < 4; ++j) {
        float4 va = xa[j];
        if (xp) {
            float4 vp = xp[j];
            va.x += vp.x; va.y += vp.y; va.z += vp.z; va.w += vp.w;
        }
        sum[4 * j] = va.x; sum[4 * j + 1] = va.y;
        sum[4 * j + 2] = va.z; sum[4 * j + 3] = va.w;
    }
}

__device__ __forceinline__ void pack_ssp_edge(const float* v, int r, int q,
                                              u16* ldsH, u16* ldsL) {
    float h[16];
#pragma unroll
    for (int k = 0; k < 16; ++k) h[k] = sspf(v[k]);
    pack_store(h, rho(r), q, ldsH, ldsL);
}

// carry-chained run merge over 16 consecutive sorted edges per thread
__device__ __forceinline__ void edge_out(const f32x4 acc[4], const u32* mix_s,
        const float* fr_s, const float2* __restrict__ gt2,
        float bb, int col, int lq, float* __restrict__ msgsum) {
    float carry = 0.f;
    int rcc = -1;
#pragma unroll
    for (int m = 3; m >= 0; --m) {
        int ebase = lq * 16 + m * 4;
        float vals[4];
        int rc[4];
#pragma unroll
        for (int r = 0; r < 4; ++r) {
            u32 mx = mix_s[ebase + r];
            rc[r] = (int)(mx >> 11);
            float2 g2 = gt2[(size_t)(mx & 2047u) * HD + col];
            vals[r] = (acc[m][r] + bb) * fmaf(g2.y - g2.x, fr_s[ebase + r], g2.x);
        }
        if (rcc == rc[3]) vals[3] += carry;
        else if (rcc >= 0) atomic_add_f(msgsum + (size_t)rcc * HD + col, carry);
#pragma unroll
        for (int r = 3; r >= 1; --r) {
            if (rc[r] == rc[r - 1]) vals[r - 1] += vals[r];
            else atomic_add_f(msgsum + (size_t)rc[r] * HD + col, vals[r]);
        }
        carry = vals[0];
        rcc = rc[0];
    }
    atomic_add_f(msgsum + (size_t)rcc * HD + col, carry);
}

// ---------- edge kernel: 2-tile pipelined ----------
__global__ __launch_bounds__(NT, 4) void edge_msg_k(
        const float* __restrict__ Xab, const float* __restrict__ Xp,
        const u16* __restrict__ W2b, const float* __restrict__ bn2,
        const float2* __restrict__ gt2, const float* __restrict__ dist,
        const int* __restrict__ pe, const u32* __restrict__ eord,
        float* __restrict__ msgsum) {
    __shared__ u16 ldsH[2][MT * 128];
    __shared__ u16 ldsL[2][MT * 128];
    __shared__ u32 mix_s[2][MT];
    __shared__ float fr_s[2][MT];
    int t = threadIdx.x;
    int lane = t & 63, wid = t >> 6;
    int l15 = lane & 15, lq = lane >> 4;
    int col = wid * 16 + l15;
    int e0 = blockIdx.x * (2 * MT);

    bf16x8 Bh[4], Bl[4];
    load_bfrags(W2b, lane, wid, Bh, Bl);
    float bb = bn2[col];

    float s0[16], s1[16];
    gather_edge(e0, t, Xab, Xp, pe, eord, dist, mix_s[0], fr_s[0], s0);
    gather_edge(e0 + MT, t, Xab, Xp, pe, eord, dist, mix_s[1], fr_s[1], s1);
    pack_ssp_edge(s0, t >> 3, t & 7, ldsH[0], ldsL[0]);
    bar_lds();

    f32x4 acc0[4] = {};
    mma_slice_pre(ldsH[0], ldsL[0], lane, Bh, Bl, acc0);
    pack_ssp_edge(s1, t >> 3, t & 7, ldsH[1], ldsL[1]);
    edge_out(acc0, mix_s[0], fr_s[0], gt2, bb, col, lq, msgsum);
    bar_lds();

    f32x4 acc1[4] = {};
    mma_slice_pre(ldsH[1], ldsL[1], lane, Bh, Bl, acc1);
    edge_out(acc1, mix_s[1], fr_s[1], gt2, bb, col, lq, msgsum);
}

// ---------- fused probe update ----------
__global__ __launch_bounds__(NT, 4) void probe_update_k(
        const float* ps, const float* msgsum, float* msgzero,
        const u16* __restrict__ gW1b, const float* __restrict__ gb1,
        const u16* __restrict__ gW2b, const float* __restrict__ gb2,
        const u16* __restrict__ tW1b, const float* __restrict__ tb1,
        const u16* __restrict__ tW2b, const float* __restrict__ tb2,
        const u16* __restrict__ W3b,
        const u16* __restrict__ rW1b, const float* __restrict__ rb1,
        const float* __restrict__ rW2, const float* __restrict__ rb2,
        const float* __restrict__ g0v,
        float* psout, float* __restrict__ xpout, float* __restrict__ outp) {
    __shared__ u16 ldsH[2][MT * 128];
    __shared__ u16 ldsL[2][MT * 128];
    __shared__ float parts[MT][9];
    int m0 = blockIdx.x * MT, t = threadIdx.x;
    int lane = t & 63, wid = t >> 6;
    int l15 = lane & 15, lq = lane >> 4;
    int col = wid * 16 + l15;

    f32x4 g[4] = {};
    f32x4 tv[4] = {};
    int vbuf;

    if (!g0v) {
        float sp[16], sm[16];
        gather_rows(ps, NPROBE, m0, t, sp);
        gather_rows(msgsum, NPROBE, m0, t, sm);
        pack_store(sp, t >> 3, t & 7, ldsH[0], ldsL[0]);
        bar_lds();
        pack_store(sm, t >> 3, t & 7, ldsH[1], ldsL[1]);
        if (msgzero) zero_rows(msgzero, NPROBE, m0, t);
        mma_slice(ldsH[0], ldsL[0], lane, wid, gW1b, g);
        bar_lds();
        h_store(ldsH[0], ldsL[0], wid, lane, g, gb1);
        mma_slice(ldsH[1], ldsL[1], lane, wid, tW1b, tv);
        bar_lds();
#pragma unroll
        for (int m = 0; m < 4; ++m) g[m] = (f32x4){0.f, 0.f, 0.f, 0.f};
        mma_slice(ldsH[0], ldsL[0], lane, wid, gW2b, g);
        float gb2v = gb2[col];
#pragma unroll
        for (int m = 0; m < 4; ++m)
#pragma unroll
            for (int r = 0; r < 4; ++r) g[m][r] = sigf(g[m][r] + gb2v);
        h_store(ldsH[1], ldsL[1], wid, lane, tv, tb1);
        bar_lds();
#pragma unroll
        for (int m = 0; m < 4; ++m) tv[m] = (f32x4){0.f, 0.f, 0.f, 0.f};
        mma_slice(ldsH[1], ldsL[1], lane, wid, tW2b, tv);
        vbuf = 0;
    } else {
        float sm[16];
        gather_rows(msgsum, NPROBE, m0, t, sm);
        pack_store(sm, t >> 3, t & 7, ldsH[0], ldsL[0]);
        if (msgzero) zero_rows(msgzero, NPROBE, m0, t);
        bar_lds();
        mma_slice(ldsH[0], ldsL[0], lane, wid, tW1b, tv);
        bar_lds();
        h_store(ldsH[0], ldsL[0], wid, lane, tv, tb1);
        bar_lds();
#pragma unroll
        for (int m = 0; m < 4; ++m) tv[m] = (f32x4){0.f, 0.f, 0.f, 0.f};
        mma_slice(ldsH[0], ldsL[0], lane, wid, tW2b, tv);
        float gv = g0v[col];
#pragma unroll
        for (int m = 0; m < 4; ++m)
#pragma unroll
            for (int r = 0; r < 4; ++r) g[m][r] = gv;
        vbuf = 1;
    }

    float tb2v = tb2[col];
#pragma unroll
    for (int m = 0; m < 4; ++m) {
#pragma unroll
        for (int r = 0; r < 4; ++r) {
            int row = m0 + m * 16 + lq * 4 + r;
            float val = 0.f;
            if (row < NPROBE) {
                size_t idx = (size_t)row * HD + col;
                float tval = tv[m][r] + tb2v;
                float pv = g0v ? 0.f : ps[idx];
                val = fmaf(pv - tval, g[m][r], tval);
                if (!rW1b) psout[idx] = val;
            }
            v_store(ldsH[vbuf], ldsL[vbuf], wid, lane, m, r, val);
        }
    }
    bar_lds();

    if (W3b) {
        f32x4 a[4] = {};
        mma_slice(ldsH[vbuf], ldsL[vbuf], lane, wid, W3b, a);
#pragma unroll
        for (int m = 0; m < 4; ++m)
#pragma unroll
            for (int r = 0; r < 4; ++r) {
                int row = m0 + m * 16 + lq * 4 + r;
                if (row < NPROBE) xpout[(size_t)row * HD + col] = a[m][r];
            }
    } else if (rW1b) {
        f32x4 a[4] = {};
        mma_slice(ldsH[vbuf], ldsL[vbuf], lane, wid, rW1b, a);
        float rb1v = rb1[col], w2v = rW2[col];
#pragma unroll
        for (int m = 0; m < 4; ++m)
#pragma unroll
            for (int r = 0; r < 4; ++r) {
                float p = sspf(a[m][r] + rb1v) * w2v;
                p += __shfl_xor(p, 1, 16);
                p += __shfl_xor(p, 2, 16);
                p += __shfl_xor(p, 4, 16);
                p += __shfl_xor(p, 8, 16);
                if (l15 == 0) parts[m * 16 + lq * 4 + r][wid] = p;
            }
        bar_lds();
        if (t < MT) {
            int row = m0 + t;
            if (row < NPROBE) {
                float s = rb2[0];
#pragma unroll
                for (int w = 0; w < 8; ++w) s += parts[t][w];
                outp[row] = s;
            }
        }
    }
}

// ---------- launcher ----------
extern "C" void kernel_launch(void* const* d_in, const int* in_sizes, int n_in,
                              void* d_out, int out_size, void* d_ws, size_t ws_size,
                              hipStream_t stream) {
    const float* atom_rep = (const float*)d_in[0];
    const float* dist     = (const float*)d_in[1];
    const float* We1 = (const float*)d_in[2];
    const float* be1 = (const float*)d_in[3];
    const float* We2 = (const float*)d_in[4];
    const float* be2 = (const float*)d_in[5];
    const float* Wn1 = (const float*)d_in[6];
    const float* bn1 = (const float*)d_in[7];
    const float* Wn2 = (const float*)d_in[8];
    const float* bn2 = (const float*)d_in[9];
    const float* gW1 = (const float*)d_in[10];
    const float* gb1 = (const float*)d_in[11];
    const float* gW2 = (const float*)d_in[12];
    const float* gb2 = (const float*)d_in[13];
    const float* tW1 = (const float*)d_in[14];
    const float* tb1 = (const float*)d_in[15];
    const float* tW2 = (const float*)d_in[16];
    const float* tb2 = (const float*)d_in[17];
    const float* rW1 = (const float*)d_in[18];
    const float* rb1 = (const float*)d_in[19];
    const float* rW2 = (const float*)d_in[20];
    const float* rb2 = (const float*)d_in[21];
    const int*   pe  = (const int*)d_in[22];
    float* out = (float*)d_out;

    float* ws = (float*)d_ws;
    float* ps     = ws;                          // 12,800,000 f
    float* msgsum = ps + 12800000u;              // 12,800,000 f
    float* Xp     = msgsum + 12800000u;          // 12,800,000 f
    float* Xab    = Xp + 12800000u;              // 3 * 2,560,000 f
    float2* gt2   = (float2*)(Xab + 7680000u);   // 3*NBIN*HD float2 = 1,572,864 f
    float* g0v    = (float*)(gt2 + (size_t)NLAYER * NBIN * HD);   // 128 f
    u16*   Wb     = (u16*)(g0v + 128);           // 22*2*PLANE u16
    u32*   cnt    = (u32*)(Wb + 22 * 2 * PLANE);
    u32*   bsum   = cnt + NPROBE;                // NSBLK
    u32*   cur    = bsum + 512;
    u32*   eord   = cur + NPROBE;

    const int PBLK = (NPROBE + MT - 1) / MT;   // 1563
    const int EBLK = NEDGE / (2 * MT);         // 3125
    const int TBLK = (NEDGE + 255) / 256;      // 1563

    hipMemsetAsync(cnt, 0, (size_t)NPROBE * 4, stream);
    hipMemsetAsync(msgsum, 0, 12800000ull * 4, stream);
    convert_w_k<<<22, 256, 0, stream>>>(Wn1, Wn2, gW1, gW2, tW1, tW2, rW1, Wb);
    gate_table_k<<<NLAYER * (NBIN + 1), HD, 0, stream>>>(We1, be1, We2, be2, gt2);
    gate0_k<<<1, HD, 0, stream>>>(gW2, gb1, gb2, g0v);
    hist_k<<<TBLK, 256, 0, stream>>>(pe, cnt);
    bsum_k<<<NSBLK, 256, 0, stream>>>(cnt, bsum);
    bscan_k<<<1, 512, 0, stream>>>(bsum);
    cur_k<<<NSBLK, 256, 0, stream>>>(cnt, bsum, cur);
    scatter_k<<<TBLK, 256, 0, stream>>>(pe, cur, eord);
    gemm_atoms_k<<<NLAYER * ABLK, NT, 0, stream>>>(atom_rep, Wb, bn1, Xab);

    for (int l = 0; l < NLAYER; ++l) {
        edge_msg_k<<<EBLK, NT, 0, stream>>>(Xab + (size_t)l * NATOM * HD,
                                            (l == 0) ? nullptr : Xp,
                                            Wb + (size_t)(6 + l) * 2 * PLANE,
                                            bn2 + l * HD,
                                            gt2 + (size_t)l * NBIN * HD,
                                            dist, pe, eord, msgsum);
        const u16* W3  = (l < NLAYER - 1) ? Wb + (size_t)(2 * (l + 1) + 1) * 2 * PLANE : nullptr;
        const u16* RW1 = (l == NLAYER - 1) ? Wb + (size_t)21 * 2 * PLANE : nullptr;
        float* mz = (l < NLAYER - 1) ? msgsum : nullptr;
        probe_update_k<<<PBLK, NT, 0, stream>>>(ps, msgsum, mz,
                                                Wb + (size_t)(9 + l) * 2 * PLANE, gb1 + l * HD,
                                                Wb + (size_t)(12 + l) * 2 * PLANE, gb2 + l * HD,
                                                Wb + (size_t)(15 + l) * 2 * PLANE, tb1 + l * HD,
                                                Wb + (size_t)(18 + l) * 2 * PLANE, tb2 + l * HD,
                                                W3, RW1, rb1, rW2, rb2,
                                                (l == 0) ? g0v : nullptr,
                                                ps, Xp, out);
    }
}